// Round 6
// baseline (368.156 us; speedup 1.0000x reference)
//
#include <hip/hip_runtime.h>
#include <hip/hip_bf16.h>
#include <math.h>

typedef short short8 __attribute__((ext_vector_type(8)));
typedef float floatx4 __attribute__((ext_vector_type(4)));
typedef int   intx4  __attribute__((ext_vector_type(4)));

#define D 128
#define Q 2500
#define QPAD 2560
#define NK 10080
#define NKPAD 10112
#define SPLITS 19
#define CPS 17   // ceil(315/19)=17 chunks of 32; last split has 9
// padded strides (avoid 4096B channel alignment)
#define OPS 163904   // u32 per split for OpartU
#define LPS 10304    // f32 per split for lpart
// vis bitmask: 315 words/row used, stride 320 u32 (1280 B)
#define VBW 320
// V LDS row pad: 40 shorts (80B, 16B-aligned stride)
#define VROW 40
// 1/sqrt(32) * log2(e)
#define QSCALE 0.25501268426834347f
#define NEGBIG -3.0e38f

__device__ __forceinline__ unsigned short f2bf(float f) {
    unsigned u = __float_as_uint(f);
    unsigned r = (u + 0x7fffu + ((u >> 16) & 1u)) >> 16;
    return (unsigned short)r;
}
__device__ __forceinline__ unsigned pack2bf(float lo, float hi) {
    unsigned u0 = __float_as_uint(lo) + 0x8000u;
    unsigned u1 = __float_as_uint(hi) + 0x8000u;
    return (u0 >> 16) | (u1 & 0xffff0000u);
}
// HW packed f32->bf16 (RNE), lo -> [15:0], hi -> [31:16]
__device__ __forceinline__ unsigned cvtpk(float lo, float hi) {
    unsigned r;
    asm("v_cvt_pk_bf16_f32 %0, %1, %2" : "=v"(r) : "v"(lo), "v"(hi));
    return r;
}
__device__ __forceinline__ float bflo(unsigned u) { return __uint_as_float(u << 16); }
__device__ __forceinline__ float bfhi(unsigned u) { return __uint_as_float(u & 0xffff0000u); }

// ---------- prep: LayerNorm tiles + weight convert + vis bit-pack (fused) ----------
__global__ __launch_bounds__(256) void prep_kernel(
    const float* __restrict__ qi, const float* __restrict__ ki, const float* __restrict__ vi,
    const float* __restrict__ qw, const float* __restrict__ qb_,
    const float* __restrict__ kw, const float* __restrict__ kb,
    const float* __restrict__ vw, const float* __restrict__ vb,
    unsigned short* __restrict__ xq, unsigned short* __restrict__ xk,
    unsigned short* __restrict__ xv,
    const float* __restrict__ wq, const float* __restrict__ wk,
    const float* __restrict__ wv, const float* __restrict__ wp,
    const float* __restrict__ w1, const float* __restrict__ w2,
    unsigned short* __restrict__ wqT, unsigned short* __restrict__ wkT,
    unsigned short* __restrict__ wvT, unsigned short* __restrict__ wpT,
    unsigned short* __restrict__ w1T, unsigned short* __restrict__ w2T,
    const int* __restrict__ vis, unsigned* __restrict__ vbits) {
    int bid = blockIdx.x, t = threadIdx.x;
    if (bid >= 1227) {
        // vis bit-pack: one row per block
        int row = bid - 1227;
        const int* src = vis + (size_t)row * NK;
        #pragma unroll 2
        for (int w = t; w < 315; w += 256) {
            unsigned bits = 0;
            const intx4* p = (const intx4*)(src + w * 32);
            #pragma unroll
            for (int g = 0; g < 8; g++) {
                intx4 v = p[g];
                #pragma unroll
                for (int j = 0; j < 4; j++) bits |= (v[j] ? 1u : 0u) << (g * 4 + j);
            }
            vbits[(size_t)row * VBW + w] = bits;
        }
        return;
    }
    if (bid >= 715) {
        int idx = (bid - 715) * 256 + t;  // 131072 total
        if (idx < 49152) {
            int m = idx >> 14;
            int local = idx & 16383;
            int n = local >> 7, kk = local & 127;
            const float* w = (m == 0) ? wq : ((m == 1) ? wk : wv);
            unsigned short* o = (m == 0) ? wqT : ((m == 1) ? wkT : wvT);
            o[local] = f2bf(w[kk * 128 + n]);
        } else if (idx < 65536) {
            int local = idx - 49152;
            int n = local >> 7, kk = local & 127;
            wpT[local] = f2bf(wp[kk * 128 + n]);
        } else if (idx < 98304) {
            int local = idx - 65536;
            int n = local >> 7, kk = local & 127;
            w1T[local] = f2bf(w1[kk * 256 + n]);
        } else {
            int local = idx - 98304;
            int n = local >> 8, kk = local & 255;
            w2T[local] = f2bf(w2[kk * 128 + n]);
        }
        return;
    }
    __shared__ float lds2[32 * 132];
    const float* src; unsigned short* dst; const float *g, *b;
    int S, valid;
    if (bid < 79) {
        int p0 = bid * 32;
        src = qi + p0; S = Q; dst = xq + p0 * D; g = qw; b = qb_;
        valid = Q - p0; if (valid > 32) valid = 32;
    } else if (bid < 397) {
        int tt = bid - 79;
        int n = tt / 53, tile = tt - n * 53, r = tile * 32;
        src = ki + (size_t)(n * 128) * 1680 + r; S = 1680;
        dst = xk + (n * 1680 + r) * D; g = kw; b = kb;
        valid = 1680 - r; if (valid > 32) valid = 32;
    } else {
        int tt = bid - 397;
        int n = tt / 53, tile = tt - n * 53, r = tile * 32;
        src = vi + (size_t)(n * 128) * 1680 + r; S = 1680;
        dst = xv + (n * 1680 + r) * D; g = vw; b = vb;
        valid = 1680 - r; if (valid > 32) valid = 32;
    }
    #pragma unroll
    for (int pass = 0; pass < 4; pass++) {
        int s = pass * 256 + t;
        int d = s >> 3, ps = s & 7;
        floatx4 val = {0.f, 0.f, 0.f, 0.f};
        if (ps * 4 < valid) val = *(const floatx4*)(src + (size_t)d * S + ps * 4);
        #pragma unroll
        for (int j = 0; j < 4; j++) lds2[(ps * 4 + j) * 132 + d] = val[j];
    }
    __syncthreads();
    int lane = t & 63, wvx = t >> 6;
    int pos = wvx * 8 + (lane >> 3), l7 = lane & 7;
    floatx4 x4[4];
    #pragma unroll
    for (int k = 0; k < 4; k++) x4[k] = *(const floatx4*)(&lds2[pos * 132 + l7 * 16 + k * 4]);
    float s = 0.f, ss = 0.f;
    #pragma unroll
    for (int k = 0; k < 4; k++)
        #pragma unroll
        for (int j = 0; j < 4; j++) { s += x4[k][j]; ss += x4[k][j] * x4[k][j]; }
    #pragma unroll
    for (int m = 1; m <= 4; m <<= 1) { s += __shfl_xor(s, m, 64); ss += __shfl_xor(ss, m, 64); }
    float mean = s * (1.0f / 128.0f);
    float var = ss * (1.0f / 128.0f) - mean * mean;
    float rstd = rsqrtf(var + 1e-5f);
    short8 o1, o2;
    #pragma unroll
    for (int k = 0; k < 4; k++) {
        floatx4 g4 = *(const floatx4*)(g + l7 * 16 + k * 4);
        floatx4 b4 = *(const floatx4*)(b + l7 * 16 + k * 4);
        #pragma unroll
        for (int j = 0; j < 4; j++) {
            float o = (x4[k][j] - mean) * rstd * g4[j] + b4[j];
            if (k < 2) o1[k * 4 + j] = (short)f2bf(o);
            else o2[(k - 2) * 4 + j] = (short)f2bf(o);
        }
    }
    if (pos < valid) {
        *(short8*)(dst + pos * D + l7 * 16) = o1;
        *(short8*)(dst + pos * D + l7 * 16 + 8) = o2;
    }
}

// ---------- Projection GEMM, vectorized weights; V written transposed ----------
__global__ __launch_bounds__(256) void proj_kernel(
    const unsigned short* __restrict__ xq, const unsigned short* __restrict__ xk,
    const unsigned short* __restrict__ xv,
    const unsigned short* __restrict__ wqT, const unsigned short* __restrict__ wkT,
    const unsigned short* __restrict__ wvT,
    const float* __restrict__ bq, const float* __restrict__ bk, const float* __restrict__ bv,
    unsigned short* __restrict__ qh, unsigned short* __restrict__ kh,
    unsigned short* __restrict__ vhT) {
    __shared__ short vlds[128 * 72];
    int bid = blockIdx.x;
    const unsigned short *src, *wT; const float* bias; int mb, mode; float scale;
    if (bid < 40)       { mode = 0; src = xq; wT = wqT; bias = bq; mb = bid * 64; scale = QSCALE; }
    else if (bid < 198) { mode = 1; src = xk; wT = wkT; bias = bk; mb = (bid - 40) * 64; scale = 1.0f; }
    else                { mode = 2; src = xv; wT = wvT; bias = bv; mb = (bid - 198) * 64; scale = 1.0f; }
    int t = threadIdx.x, wave = t >> 6, lane = t & 63;
    int l15 = lane & 15, quad = lane >> 4;
    int m0 = mb + wave * 16;
    floatx4 acc[8];
    #pragma unroll
    for (int i = 0; i < 8; i++) acc[i] = (floatx4){0.f, 0.f, 0.f, 0.f};
    #pragma unroll
    for (int kf = 0; kf < 4; kf++) {
        short8 A = *(const short8*)(src + (m0 + l15) * D + kf * 32 + quad * 8);
        #pragma unroll
        for (int nt = 0; nt < 8; nt++) {
            short8 Bv = *(const short8*)(wT + (nt * 16 + l15) * D + kf * 32 + quad * 8);
            acc[nt] = __builtin_amdgcn_mfma_f32_16x16x32_bf16(A, Bv, acc[nt], 0, 0, 0);
        }
    }
    if (mode != 2) {
        unsigned short* dst = (mode == 0) ? qh : kh;
        #pragma unroll
        for (int nt = 0; nt < 8; nt++) {
            float bb = bias[nt * 16 + l15];
            #pragma unroll
            for (int r = 0; r < 4; r++)
                dst[(m0 + quad * 4 + r) * D + nt * 16 + l15] = f2bf((acc[nt][r] + bb) * scale);
        }
    } else {
        #pragma unroll
        for (int nt = 0; nt < 8; nt++) {
            float bb = bias[nt * 16 + l15];
            #pragma unroll
            for (int r = 0; r < 4; r++)
                vlds[(nt * 16 + l15) * 72 + (wave * 16 + quad * 4 + r)] =
                    (short)f2bf(acc[nt][r] + bb);
        }
        __syncthreads();
        int pr = t & 31, dd = t >> 5;
        int sub = pr >> 4, i = pr & 15;
        #pragma unroll
        for (int pass = 0; pass < 16; pass++) {
            int d = pass * 8 + dd;
            unsigned lo = (unsigned short)vlds[d * 72 + sub * 32 + i];
            unsigned hi = (unsigned short)vlds[d * 72 + sub * 32 + 16 + i];
            *(unsigned*)(vhT + (size_t)d * NKPAD + mb + sub * 32 + 2 * i) = lo | (hi << 16);
        }
    }
}

// ---------- Fused attention v11: shuffle P-transform (no Pl), LDS 37888 -> 3 blk/CU ----------
template<int USEBITS>
__global__ __launch_bounds__(256, 3) void attn_kernel_t(
    const unsigned short* __restrict__ qh, const unsigned short* __restrict__ kh,
    const unsigned short* __restrict__ vhT,
    const float* __restrict__ Wl, const int* __restrict__ vis,
    const unsigned* __restrict__ vbits,
    unsigned* __restrict__ OpartU, float* __restrict__ lpart) {
    __shared__ short Kl[2][32 * 136];   // K chunk [k][d] pad 136 -> 17408 B
    __shared__ short Vl[2][128 * VROW]; // V^T chunk [d][k] pad 40 -> 20480 B ; total 37888
    int bid = blockIdx.x;
    int split = bid % SPLITS, qt = bid / SPLITS;
    int t = threadIdx.x, wave = t >> 6, lane = t & 63;
    int l15 = lane & 15, quad = lane >> 4;
    int qb = qt * 64 + wave * 16;
    int k00 = split * (CPS * 32);
    int cmax = (NK - k00) >> 5; if (cmax > CPS) cmax = CPS;  // last split: 9

    // Q fragments (loop-invariant), B-operand layout
    short8 qB[4];
    #pragma unroll
    for (int h = 0; h < 4; h++)
        qB[h] = *(const short8*)(qh + (size_t)(qb + l15) * D + h * 32 + quad * 8);

    // staging assignment: K: thread -> row kr, 2x16B segs; V: row vd, 2x16B segs
    int kr = t >> 3, ks = (t & 7) * 2;
    int vd = t >> 1, vs = (t & 1) * 2;
    const uint4* ksrc = (const uint4*)(kh + (size_t)(k00 + kr) * D + ks * 8);
    const uint4* vsrc = (const uint4*)(vhT + (size_t)vd * NKPAD + k00 + vs * 8);
    short* kdst = &Kl[0][kr * 136 + ks * 8];
    short* vdst = &Vl[0][vd * VROW + vs * 8];

    // W/vis per lane: q = qb+l15, k = quad*4..+3 (+16)
    int wrow = qb + l15; if (wrow >= Q) wrow = Q - 1;
    const float* wp = Wl + (size_t)wrow * NK + k00 + quad * 4;
    const int*   vp = vis + (size_t)wrow * NK + k00 + quad * 4;
    const unsigned* vbp = vbits + (size_t)wrow * VBW + split * CPS;

    // shuffle indices for the P C->B transform (loop-invariant; verified round-3)
    int idxA = l15 + ((quad & 1) << 5);
    int idxB = idxA + 16;
    bool hiK = (quad >= 2);

    const floatx4 zf = {0.f, 0.f, 0.f, 0.f};
    floatx4 O[4][2];
    float lacc[4];
    #pragma unroll
    for (int h = 0; h < 4; h++) { O[h][0] = zf; O[h][1] = zf; lacc[h] = 0.f; }

    // prologue: chunk 0
    uint4 ka = ksrc[0], kb2 = ksrc[1];
    uint4 va = vsrc[0], vb2 = vsrc[1];
    floatx4 wc0 = *(const floatx4*)wp;
    floatx4 wc1 = *(const floatx4*)(wp + 16);
    intx4 vc0, vc1;
    unsigned vbc = 0;
    if constexpr (USEBITS) {
        vbc = vbp[0];
    } else {
        vc0 = *(const intx4*)vp;
        vc1 = *(const intx4*)(vp + 16);
    }
    *(uint4*)kdst = ka;       *(uint4*)(kdst + 8) = kb2;
    *(uint4*)vdst = va;       *(uint4*)(vdst + 8) = vb2;

    #pragma unroll 1
    for (int c = 0; c < cmax; c++) {
        __syncthreads();
        int buf = c & 1;
        uint4 nka, nkb, nva, nvb;
        floatx4 wn0, wn1; intx4 vn0, vn1;
        unsigned vbn = 0;
        if (c + 1 < cmax) {
            const uint4* ks2 = ksrc + (size_t)(c + 1) * 512;
            const uint4* vs2 = vsrc + (size_t)(c + 1) * 4;
            nka = ks2[0]; nkb = ks2[1];
            nva = vs2[0]; nvb = vs2[1];
            wn0 = *(const floatx4*)(wp + (c + 1) * 32);
            wn1 = *(const floatx4*)(wp + (c + 1) * 32 + 16);
            if constexpr (USEBITS) {
                vbn = vbp[c + 1];
            } else {
                vn0 = *(const intx4*)(vp + (c + 1) * 32);
                vn1 = *(const intx4*)(vp + (c + 1) * 32 + 16);
            }
        }
        float a2[8], b2[8];
        if constexpr (USEBITS) {
            unsigned bq = vbc >> (quad * 4);
            #pragma unroll
            for (int r = 0; r < 4; r++) {
                bool m0 = (bq >> r) & 1u;
                bool m1 = (bq >> (16 + r)) & 1u;
                a2[r]     = m0 ? wc0[r] : 0.f;
                b2[r]     = m0 ? 0.f : wc0[r] * NEGBIG;
                a2[4 + r] = m1 ? wc1[r] : 0.f;
                b2[4 + r] = m1 ? 0.f : wc1[r] * NEGBIG;
            }
        } else {
            #pragma unroll
            for (int r = 0; r < 4; r++) {
                a2[r]     = vc0[r] ? wc0[r] : 0.f;
                b2[r]     = vc0[r] ? 0.f : wc0[r] * NEGBIG;
                a2[4 + r] = vc1[r] ? wc1[r] : 0.f;
                b2[4 + r] = vc1[r] ? 0.f : wc1[r] * NEGBIG;
            }
        }
        const short* Kb = Kl[buf];
        const short* Vb = Vl[buf];
        #pragma unroll
        for (int h = 0; h < 4; h++) {
            short8 kA0 = *(const short8*)(Kb + l15 * 136 + h * 32 + quad * 8);
            short8 kA1 = *(const short8*)(Kb + (16 + l15) * 136 + h * 32 + quad * 8);
            floatx4 S0 = __builtin_amdgcn_mfma_f32_16x16x32_bf16(kA0, qB[h], zf, 0, 0, 0);
            floatx4 S1 = __builtin_amdgcn_mfma_f32_16x16x32_bf16(kA1, qB[h], zf, 0, 0, 0);
            float p0[4], p1[4];
            #pragma unroll
            for (int r = 0; r < 4; r++) {
                p0[r] = exp2f(S0[r] * a2[r] + b2[r]);
                p1[r] = exp2f(S1[r] * a2[4 + r] + b2[4 + r]);
                lacc[h] += p0[r] + p1[r];
            }
            // P C->B transform in-register: 4 cvt_pk + 8 bpermute + 4 selects.
            // Source lane (l15, qs) holds kpairs {2qs,2qs+1} in u0,u1 (S0) and
            // {8+2qs,9+2qs} in u2,u3 (S1). Target (l15, quad) needs kpairs
            // 4*quad+j from lanes l15+(quad&1)*32 (+16); u0/u1 if quad<2 else u2/u3.
            unsigned u0 = cvtpk(p0[0], p0[1]);
            unsigned u1 = cvtpk(p0[2], p0[3]);
            unsigned u2 = cvtpk(p1[0], p1[1]);
            unsigned u3 = cvtpk(p1[2], p1[3]);
            unsigned s0A = __shfl(u0, idxA, 64), s2A = __shfl(u2, idxA, 64);
            unsigned s1A = __shfl(u1, idxA, 64), s3A = __shfl(u3, idxA, 64);
            unsigned s0B = __shfl(u0, idxB, 64), s2B = __shfl(u2, idxB, 64);
            unsigned s1B = __shfl(u1, idxB, 64), s3B = __shfl(u3, idxB, 64);
            union { unsigned u[4]; short8 s8; } pb;
            pb.u[0] = hiK ? s2A : s0A;
            pb.u[1] = hiK ? s3A : s1A;
            pb.u[2] = hiK ? s2B : s0B;
            pb.u[3] = hiK ? s3B : s1B;
            short8 vA0 = *(const short8*)(Vb + (h * 32 + l15) * VROW + quad * 8);
            short8 vA1 = *(const short8*)(Vb + (h * 32 + 16 + l15) * VROW + quad * 8);
            O[h][0] = __builtin_amdgcn_mfma_f32_16x16x32_bf16(vA0, pb.s8, O[h][0], 0, 0, 0);
            O[h][1] = __builtin_amdgcn_mfma_f32_16x16x32_bf16(vA1, pb.s8, O[h][1], 0, 0, 0);
        }
        if (c + 1 < cmax) {
            short* kd = buf ? kdst : (kdst + 32 * 136);
            short* vd2 = buf ? vdst : (vdst + 128 * VROW);
            *(uint4*)kd = nka;       *(uint4*)(kd + 8) = nkb;
            *(uint4*)vd2 = nva;      *(uint4*)(vd2 + 8) = nvb;
            wc0 = wn0; wc1 = wn1;
            if constexpr (USEBITS) { vbc = vbn; }
            else { vc0 = vn0; vc1 = vn1; }
        }
    }

    int row = qb + l15;
    #pragma unroll
    for (int h = 0; h < 4; h++) {
        float lv = lacc[h];
        lv += __shfl_xor(lv, 16, 64);
        lv += __shfl_xor(lv, 32, 64);
        if (quad == 0) lpart[(size_t)split * LPS + row * 4 + h] = lv;
        #pragma unroll
        for (int tl = 0; tl < 2; tl++) {
            uint2 o2;
            o2.x = cvtpk(O[h][tl][0], O[h][tl][1]);
            o2.y = cvtpk(O[h][tl][2], O[h][tl][3]);
            *(uint2*)(OpartU + (size_t)split * OPS + ((size_t)row * 4 + h) * 16 + tl * 8 + quad * 2) = o2;
        }
    }
}

// ---------- MLP epilogue with inline split-combine (round-0 structure, 19 splits) ----------
__global__ __launch_bounds__(256) void mlp_kernel(
    const unsigned* __restrict__ Opart, const float* __restrict__ lpart,
    const unsigned short* __restrict__ wpT,
    const float* __restrict__ bp, const float* __restrict__ skip,
    const float* __restrict__ pre_w, const float* __restrict__ pre_b,
    const unsigned short* __restrict__ w1T, const float* __restrict__ b1,
    const unsigned short* __restrict__ w2T, const float* __restrict__ b2,
    const float* __restrict__ post_w, const float* __restrict__ post_b,
    float* __restrict__ out) {
    __shared__ __align__(16) char smem[68608];
    short* A1l = (short*)smem;             // [64][136] bf16
    short* Z1 = (short*)(smem + 17408);    // [64][136]
    short* H1 = (short*)(smem + 34816);    // [64][264]
    float* Zout = (float*)(smem + 17408);  // [128][65] overlay after barrier
    unsigned* A1u = (unsigned*)smem;

    int qb = blockIdx.x * 64;
    int t = threadIdx.x, wave = t >> 6, lane = t & 63;
    int l15 = lane & 15, quad = lane >> 4;
    int m0 = wave * 16;

    // inline combine: thread -> (row = t>>2, head = t&3), 16 u32 slots
    {
        int row = t >> 2, he = t & 3;
        int grow = qb + row;
        float lsum = 0.f;
        #pragma unroll 5
        for (int sp = 0; sp < SPLITS; sp++) lsum += lpart[(size_t)sp * LPS + grow * 4 + he];
        float inv = 1.0f / fmaxf(lsum, 1e-30f);
        size_t base = ((size_t)grow * 4 + he) * 16;
        #pragma unroll
        for (int sl = 0; sl < 4; sl++) {
            float a0 = 0.f, a1 = 0.f, a2 = 0.f, a3 = 0.f, a4 = 0.f, a5 = 0.f, a6 = 0.f, a7 = 0.f;
            #pragma unroll 5
            for (int sp = 0; sp < SPLITS; sp++) {
                uint4 u = *(const uint4*)(Opart + (size_t)sp * OPS + base + sl * 4);
                a0 += bflo(u.x); a1 += bfhi(u.x);
                a2 += bflo(u.y); a3 += bfhi(u.y);
                a4 += bflo(u.z); a5 += bfhi(u.z);
                a6 += bflo(u.w); a7 += bfhi(u.w);
            }
            int o = row * 68 + he * 16 + sl * 4;
            A1u[o + 0] = pack2bf(a0 * inv, a1 * inv);
            A1u[o + 1] = pack2bf(a2 * inv, a3 * inv);
            A1u[o + 2] = pack2bf(a4 * inv, a5 * inv);
            A1u[o + 3] = pack2bf(a6 * inv, a7 * inv);
        }
    }
    __syncthreads();

    // G1: Z = A1 @ wp
    floatx4 z[8];
    #pragma unroll
    for (int i = 0; i < 8; i++) z[i] = (floatx4){0.f, 0.f, 0.f, 0.f};
    #pragma unroll
    for (int kf = 0; kf < 4; kf++) {
        short8 A = *(const short8*)(A1l + (m0 + l15) * 136 + kf * 32 + quad * 8);
        #pragma unroll
        for (int nt = 0; nt < 8; nt++) {
            short8 Bv = *(const short8*)(wpT + (nt * 16 + l15) * D + kf * 32 + quad * 8);
            z[nt] = __builtin_amdgcn_mfma_f32_16x16x32_bf16(A, Bv, z[nt], 0, 0, 0);
        }
    }
    float Zv[8][4];
    #pragma unroll
    for (int nt = 0; nt < 8; nt++) {
        int n = nt * 16 + l15;
        float bb = bp[n];
        #pragma unroll
        for (int r = 0; r < 4; r++) {
            int q = qb + m0 + quad * 4 + r;
            int qc = q < Q ? q : (Q - 1);
            Zv[nt][r] = z[nt][r] + bb + skip[n * Q + qc];
        }
    }
    // pre-LN
    float Zn[8][4];
    {
        #pragma unroll
        for (int r = 0; r < 4; r++) {
            float s1 = 0.f, s2 = 0.f;
            #pragma unroll
            for (int nt = 0; nt < 8; nt++) { s1 += Zv[nt][r]; s2 += Zv[nt][r] * Zv[nt][r]; }
            #pragma unroll
            for (int m = 1; m <= 8; m <<= 1) { s1 += __shfl_xor(s1, m, 64); s2 += __shfl_xor(s2, m, 64); }
            float mean = s1 * (1.0f / 128.0f);
            float var = s2 * (1.0f / 128.0f) - mean * mean;
            float rstd = rsqrtf(var + 1e-5f);
            #pragma unroll
            for (int nt = 0; nt < 8; nt++) Zn[nt][r] = (Zv[nt][r] - mean) * rstd;
        }
        #pragma unroll
        for (int nt = 0; nt < 8; nt++) {
            int n = nt * 16 + l15;
            float g = pre_w[n], be = pre_b[n];
            #pragma unroll
            for (int r = 0; r < 4; r++) {
                Zn[nt][r] = Zn[nt][r] * g + be;
                Z1[(m0 + quad * 4 + r) * 136 + n] = (short)f2bf(Zn[nt][r]);
            }
        }
    }
    // G2: H = gelu(Z1 @ w1 + b1)
    {
        floatx4 h2[16];
        #pragma unroll
        for (int i = 0; i < 16; i++) h2[i] = (floatx4){0.f, 0.f, 0.f, 0.f};
        #pragma unroll
        for (int kf = 0; kf < 4; kf++) {
            short8 A = *(const short8*)(Z1 + (m0 + l15) * 136 + kf * 32 + quad * 8);
            #pragma unroll
            for (int nt = 0; nt < 16; nt++) {
                short8 Bv = *(const short8*)(w1T + (nt * 16 + l15) * D + kf * 32 + quad * 8);
                h2[nt] = __builtin_amdgcn_mfma_f32_16x16x32_bf16(A, Bv, h2[nt], 0, 0, 0);
            }
        }
        #pragma unroll
        for (int nt = 0; nt < 16; nt++) {
            int n = nt * 16 + l15;
            float bb = b1[n];
            #pragma unroll
            for (int r = 0; r < 4; r++) {
                float x = h2[nt][r] + bb;
                float gl = 0.5f * x * (1.0f + erff(x * 0.70710678118654752f));
                H1[(m0 + quad * 4 + r) * 264 + n] = (short)f2bf(gl);
            }
        }
    }
    // G3: R = H1 @ w2 + b2; Z2 = Zn + R
    floatx4 o3[8];
    #pragma unroll
    for (int i = 0; i < 8; i++) o3[i] = (floatx4){0.f, 0.f, 0.f, 0.f};
    #pragma unroll
    for (int kf = 0; kf < 8; kf++) {
        short8 A = *(const short8*)(H1 + (m0 + l15) * 264 + kf * 32 + quad * 8);
        #pragma unroll
        for (int nt = 0; nt < 8; nt++) {
            short8 Bv = *(const short8*)(w2T + (nt * 16 + l15) * 256 + kf * 32 + quad * 8);
            o3[nt] = __builtin_amdgcn_mfma_f32_16x16x32_bf16(A, Bv, o3[nt], 0, 0, 0);
        }
    }
    float Z2[8][4];
    #pragma unroll
    for (int nt = 0; nt < 8; nt++) {
        int n = nt * 16 + l15;
        float bb = b2[n];
        #pragma unroll
        for (int r = 0; r < 4; r++) Z2[nt][r] = Zn[nt][r] + o3[nt][r] + bb;
    }
    // post-LN
    float Zo[8][4];
    {
        #pragma unroll
        for (int r = 0; r < 4; r++) {
            float s1 = 0.f, s2 = 0.f;
            #pragma unroll
            for (int nt = 0; nt < 8; nt++) { s1 += Z2[nt][r]; s2 += Z2[nt][r] * Z2[nt][r]; }
            #pragma unroll
            for (int m = 1; m <= 8; m <<= 1) { s1 += __shfl_xor(s1, m, 64); s2 += __shfl_xor(s2, m, 64); }
            float mean = s1 * (1.0f / 128.0f);
            float var = s2 * (1.0f / 128.0f) - mean * mean;
            float rstd = rsqrtf(var + 1e-5f);
            #pragma unroll
            for (int nt = 0; nt < 8; nt++) Zo[nt][r] = (Z2[nt][r] - mean) * rstd;
        }
        #pragma unroll
        for (int nt = 0; nt < 8; nt++) {
            int n = nt * 16 + l15;
            float g = post_w[n], be = post_b[n];
            #pragma unroll
            for (int r = 0; r < 4; r++) Zo[nt][r] = Zo[nt][r] * g + be;
        }
    }
    __syncthreads();
    #pragma unroll
    for (int nt = 0; nt < 8; nt++)
        #pragma unroll
        for (int r = 0; r < 4; r++)
            Zout[(nt * 16 + l15) * 65 + m0 + quad * 4 + r] = Zo[nt][r];
    __syncthreads();
    {
        int pl = t & 63;
        int q = qb + pl;
        if (q < Q) {
            #pragma unroll
            for (int it = 0; it < 32; it++) {
                int n = it * 4 + (t >> 6);
                out[n * Q + q] = Zout[n * 65 + pl];
            }
        }
    }
}

extern "C" void kernel_launch(void* const* d_in, const int* in_sizes, int n_in,
                              void* d_out, int out_size, void* d_ws, size_t ws_size,
                              hipStream_t stream) {
    (void)in_sizes; (void)n_in; (void)out_size;
    const float* q      = (const float*)d_in[0];
    const float* k      = (const float*)d_in[1];
    const float* v      = (const float*)d_in[2];
    const float* Wl     = (const float*)d_in[3];
    const int*   vis    = (const int*)  d_in[4];
    const float* skip   = (const float*)d_in[5];
    const float* qn_w   = (const float*)d_in[6];
    const float* qn_b   = (const float*)d_in[7];
    const float* kn_w   = (const float*)d_in[8];
    const float* kn_b   = (const float*)d_in[9];
    const float* vn_w   = (const float*)d_in[10];
    const float* vn_b   = (const float*)d_in[11];
    const float* pre_w  = (const float*)d_in[12];
    const float* pre_b  = (const float*)d_in[13];
    const float* post_w = (const float*)d_in[14];
    const float* post_b = (const float*)d_in[15];
    const float* wq     = (const float*)d_in[16];
    const float* bq     = (const float*)d_in[17];
    const float* wk     = (const float*)d_in[18];
    const float* bk     = (const float*)d_in[19];
    const float* wv     = (const float*)d_in[20];
    const float* bv     = (const float*)d_in[21];
    const float* wp     = (const float*)d_in[22];
    const float* bp     = (const float*)d_in[23];
    const float* w1     = (const float*)d_in[24];
    const float* b1     = (const float*)d_in[25];
    const float* w2     = (const float*)d_in[26];
    const float* b2     = (const float*)d_in[27];
    float* out = (float*)d_out;

    char* ws = (char*)d_ws;
    unsigned short* xq  = (unsigned short*)(ws + 0);          //  2560*128 bf16
    unsigned short* xk  = (unsigned short*)(ws + 655360);     // 10112*128 bf16
    unsigned short* xv  = (unsigned short*)(ws + 3244032);
    unsigned short* qh  = (unsigned short*)(ws + 5832704);
    unsigned short* kh  = (unsigned short*)(ws + 6488064);
    unsigned short* vhT = (unsigned short*)(ws + 9076736);    // [128][10112] bf16
    unsigned short* wqT = (unsigned short*)(ws + 11665408);
    unsigned short* wkT = (unsigned short*)(ws + 11698176);
    unsigned short* wvT = (unsigned short*)(ws + 11730944);
    unsigned short* wpT = (unsigned short*)(ws + 11763712);
    unsigned short* w1T = (unsigned short*)(ws + 11796480);
    unsigned short* w2T = (unsigned short*)(ws + 11862016);
    unsigned* OpartU    = (unsigned*)(ws + 11927552);         // 19*OPS u32 (padded stride)
    float* lpart        = (float*)(ws + 34874112);            // 19*LPS f32
    unsigned* vbits     = (unsigned*)(ws + 36316672);         // 2500*320 u32 = 3.2 MB
    // high-water: ~39.6 MB (packed path) / ~36.3 MB (fallback)

    const bool usebits = (ws_size == 0) || (ws_size >= 39520000ull);

    prep_kernel<<<dim3(usebits ? 3727 : 1227), dim3(256), 0, stream>>>(
        q, k, v, qn_w, qn_b, kn_w, kn_b, vn_w, vn_b, xq, xk, xv,
        wq, wk, wv, wp, w1, w2, wqT, wkT, wvT, wpT, w1T, w2T, vis, vbits);
    proj_kernel<<<dim3(356), dim3(256), 0, stream>>>(xq, xk, xv, wqT, wkT, wvT, bq, bk, bv,
                                                     qh, kh, vhT);
    if (usebits)
        attn_kernel_t<1><<<dim3(40 * SPLITS), dim3(256), 0, stream>>>(
            qh, kh, vhT, Wl, vis, vbits, OpartU, lpart);
    else
        attn_kernel_t<0><<<dim3(40 * SPLITS), dim3(256), 0, stream>>>(
            qh, kh, vhT, Wl, vis, vbits, OpartU, lpart);
    mlp_kernel<<<dim3(40), dim3(256), 0, stream>>>(OpartU, lpart, wpT, bp, skip,
                                                   pre_w, pre_b, w1T, b1, w2T, b2,
                                                   post_w, post_b, out);
}

// Round 7
// 360.230 us; speedup vs baseline: 1.0220x; 1.0220x over previous
//
#include <hip/hip_runtime.h>
#include <hip/hip_bf16.h>
#include <math.h>

typedef short short8 __attribute__((ext_vector_type(8)));
typedef float floatx4 __attribute__((ext_vector_type(4)));
typedef int   intx4  __attribute__((ext_vector_type(4)));

#define D 128
#define Q 2500
#define QPAD 2560
#define NK 10080
#define NKPAD 10112
#define SPLITS 19
#define CPS 17   // ceil(315/19)=17 chunks of 32; last split has 9
// padded strides (avoid 4096B channel alignment)
#define OPS 163904   // u32 per split for OpartU
#define LPS 10304    // f32 per split for lpart
// vis bitmask: 315 words/row used, stride 320 u32 (1280 B)
#define VBW 320
// V LDS row pad: 40 shorts (80B, 16B-aligned stride)
#define VROW 40
// 1/sqrt(32) * log2(e)
#define QSCALE 0.25501268426834347f
#define NEGBIG -3.0e38f

__device__ __forceinline__ unsigned short f2bf(float f) {
    unsigned u = __float_as_uint(f);
    unsigned r = (u + 0x7fffu + ((u >> 16) & 1u)) >> 16;
    return (unsigned short)r;
}
__device__ __forceinline__ unsigned pack2bf(float lo, float hi) {
    unsigned u0 = __float_as_uint(lo) + 0x8000u;
    unsigned u1 = __float_as_uint(hi) + 0x8000u;
    return (u0 >> 16) | (u1 & 0xffff0000u);
}
// HW packed f32->bf16 (RNE), lo -> [15:0], hi -> [31:16]
__device__ __forceinline__ unsigned cvtpk(float lo, float hi) {
    unsigned r;
    asm("v_cvt_pk_bf16_f32 %0, %1, %2" : "=v"(r) : "v"(lo), "v"(hi));
    return r;
}
__device__ __forceinline__ float bflo(unsigned u) { return __uint_as_float(u << 16); }
__device__ __forceinline__ float bfhi(unsigned u) { return __uint_as_float(u & 0xffff0000u); }

// ---------- prep: LayerNorm tiles + weight convert + vis bit-pack (fused) ----------
__global__ __launch_bounds__(256) void prep_kernel(
    const float* __restrict__ qi, const float* __restrict__ ki, const float* __restrict__ vi,
    const float* __restrict__ qw, const float* __restrict__ qb_,
    const float* __restrict__ kw, const float* __restrict__ kb,
    const float* __restrict__ vw, const float* __restrict__ vb,
    unsigned short* __restrict__ xq, unsigned short* __restrict__ xk,
    unsigned short* __restrict__ xv,
    const float* __restrict__ wq, const float* __restrict__ wk,
    const float* __restrict__ wv, const float* __restrict__ wp,
    const float* __restrict__ w1, const float* __restrict__ w2,
    unsigned short* __restrict__ wqT, unsigned short* __restrict__ wkT,
    unsigned short* __restrict__ wvT, unsigned short* __restrict__ wpT,
    unsigned short* __restrict__ w1T, unsigned short* __restrict__ w2T,
    const int* __restrict__ vis, unsigned* __restrict__ vbits) {
    int bid = blockIdx.x, t = threadIdx.x;
    if (bid >= 1227) {
        // vis bit-pack: one row per block
        int row = bid - 1227;
        const int* src = vis + (size_t)row * NK;
        #pragma unroll 2
        for (int w = t; w < 315; w += 256) {
            unsigned bits = 0;
            const intx4* p = (const intx4*)(src + w * 32);
            #pragma unroll
            for (int g = 0; g < 8; g++) {
                intx4 v = p[g];
                #pragma unroll
                for (int j = 0; j < 4; j++) bits |= (v[j] ? 1u : 0u) << (g * 4 + j);
            }
            vbits[(size_t)row * VBW + w] = bits;
        }
        return;
    }
    if (bid >= 715) {
        int idx = (bid - 715) * 256 + t;  // 131072 total
        if (idx < 49152) {
            int m = idx >> 14;
            int local = idx & 16383;
            int n = local >> 7, kk = local & 127;
            const float* w = (m == 0) ? wq : ((m == 1) ? wk : wv);
            unsigned short* o = (m == 0) ? wqT : ((m == 1) ? wkT : wvT);
            o[local] = f2bf(w[kk * 128 + n]);
        } else if (idx < 65536) {
            int local = idx - 49152;
            int n = local >> 7, kk = local & 127;
            wpT[local] = f2bf(wp[kk * 128 + n]);
        } else if (idx < 98304) {
            int local = idx - 65536;
            int n = local >> 7, kk = local & 127;
            w1T[local] = f2bf(w1[kk * 256 + n]);
        } else {
            int local = idx - 98304;
            int n = local >> 8, kk = local & 255;
            w2T[local] = f2bf(w2[kk * 128 + n]);
        }
        return;
    }
    __shared__ float lds2[32 * 132];
    const float* src; unsigned short* dst; const float *g, *b;
    int S, valid;
    if (bid < 79) {
        int p0 = bid * 32;
        src = qi + p0; S = Q; dst = xq + p0 * D; g = qw; b = qb_;
        valid = Q - p0; if (valid > 32) valid = 32;
    } else if (bid < 397) {
        int tt = bid - 79;
        int n = tt / 53, tile = tt - n * 53, r = tile * 32;
        src = ki + (size_t)(n * 128) * 1680 + r; S = 1680;
        dst = xk + (n * 1680 + r) * D; g = kw; b = kb;
        valid = 1680 - r; if (valid > 32) valid = 32;
    } else {
        int tt = bid - 397;
        int n = tt / 53, tile = tt - n * 53, r = tile * 32;
        src = vi + (size_t)(n * 128) * 1680 + r; S = 1680;
        dst = xv + (n * 1680 + r) * D; g = vw; b = vb;
        valid = 1680 - r; if (valid > 32) valid = 32;
    }
    #pragma unroll
    for (int pass = 0; pass < 4; pass++) {
        int s = pass * 256 + t;
        int d = s >> 3, ps = s & 7;
        floatx4 val = {0.f, 0.f, 0.f, 0.f};
        if (ps * 4 < valid) val = *(const floatx4*)(src + (size_t)d * S + ps * 4);
        #pragma unroll
        for (int j = 0; j < 4; j++) lds2[(ps * 4 + j) * 132 + d] = val[j];
    }
    __syncthreads();
    int lane = t & 63, wvx = t >> 6;
    int pos = wvx * 8 + (lane >> 3), l7 = lane & 7;
    floatx4 x4[4];
    #pragma unroll
    for (int k = 0; k < 4; k++) x4[k] = *(const floatx4*)(&lds2[pos * 132 + l7 * 16 + k * 4]);
    float s = 0.f, ss = 0.f;
    #pragma unroll
    for (int k = 0; k < 4; k++)
        #pragma unroll
        for (int j = 0; j < 4; j++) { s += x4[k][j]; ss += x4[k][j] * x4[k][j]; }
    #pragma unroll
    for (int m = 1; m <= 4; m <<= 1) { s += __shfl_xor(s, m, 64); ss += __shfl_xor(ss, m, 64); }
    float mean = s * (1.0f / 128.0f);
    float var = ss * (1.0f / 128.0f) - mean * mean;
    float rstd = rsqrtf(var + 1e-5f);
    short8 o1, o2;
    #pragma unroll
    for (int k = 0; k < 4; k++) {
        floatx4 g4 = *(const floatx4*)(g + l7 * 16 + k * 4);
        floatx4 b4 = *(const floatx4*)(b + l7 * 16 + k * 4);
        #pragma unroll
        for (int j = 0; j < 4; j++) {
            float o = (x4[k][j] - mean) * rstd * g4[j] + b4[j];
            if (k < 2) o1[k * 4 + j] = (short)f2bf(o);
            else o2[(k - 2) * 4 + j] = (short)f2bf(o);
        }
    }
    if (pos < valid) {
        *(short8*)(dst + pos * D + l7 * 16) = o1;
        *(short8*)(dst + pos * D + l7 * 16 + 8) = o2;
    }
}

// ---------- Projection GEMM, vectorized weights; V written transposed ----------
__global__ __launch_bounds__(256) void proj_kernel(
    const unsigned short* __restrict__ xq, const unsigned short* __restrict__ xk,
    const unsigned short* __restrict__ xv,
    const unsigned short* __restrict__ wqT, const unsigned short* __restrict__ wkT,
    const unsigned short* __restrict__ wvT,
    const float* __restrict__ bq, const float* __restrict__ bk, const float* __restrict__ bv,
    unsigned short* __restrict__ qh, unsigned short* __restrict__ kh,
    unsigned short* __restrict__ vhT) {
    __shared__ short vlds[128 * 72];
    int bid = blockIdx.x;
    const unsigned short *src, *wT; const float* bias; int mb, mode; float scale;
    if (bid < 40)       { mode = 0; src = xq; wT = wqT; bias = bq; mb = bid * 64; scale = QSCALE; }
    else if (bid < 198) { mode = 1; src = xk; wT = wkT; bias = bk; mb = (bid - 40) * 64; scale = 1.0f; }
    else                { mode = 2; src = xv; wT = wvT; bias = bv; mb = (bid - 198) * 64; scale = 1.0f; }
    int t = threadIdx.x, wave = t >> 6, lane = t & 63;
    int l15 = lane & 15, quad = lane >> 4;
    int m0 = mb + wave * 16;
    floatx4 acc[8];
    #pragma unroll
    for (int i = 0; i < 8; i++) acc[i] = (floatx4){0.f, 0.f, 0.f, 0.f};
    #pragma unroll
    for (int kf = 0; kf < 4; kf++) {
        short8 A = *(const short8*)(src + (m0 + l15) * D + kf * 32 + quad * 8);
        #pragma unroll
        for (int nt = 0; nt < 8; nt++) {
            short8 Bv = *(const short8*)(wT + (nt * 16 + l15) * D + kf * 32 + quad * 8);
            acc[nt] = __builtin_amdgcn_mfma_f32_16x16x32_bf16(A, Bv, acc[nt], 0, 0, 0);
        }
    }
    if (mode != 2) {
        unsigned short* dst = (mode == 0) ? qh : kh;
        #pragma unroll
        for (int nt = 0; nt < 8; nt++) {
            float bb = bias[nt * 16 + l15];
            #pragma unroll
            for (int r = 0; r < 4; r++)
                dst[(m0 + quad * 4 + r) * D + nt * 16 + l15] = f2bf((acc[nt][r] + bb) * scale);
        }
    } else {
        #pragma unroll
        for (int nt = 0; nt < 8; nt++) {
            float bb = bias[nt * 16 + l15];
            #pragma unroll
            for (int r = 0; r < 4; r++)
                vlds[(nt * 16 + l15) * 72 + (wave * 16 + quad * 4 + r)] =
                    (short)f2bf(acc[nt][r] + bb);
        }
        __syncthreads();
        int pr = t & 31, dd = t >> 5;
        int sub = pr >> 4, i = pr & 15;
        #pragma unroll
        for (int pass = 0; pass < 16; pass++) {
            int d = pass * 8 + dd;
            unsigned lo = (unsigned short)vlds[d * 72 + sub * 32 + i];
            unsigned hi = (unsigned short)vlds[d * 72 + sub * 32 + 16 + i];
            *(unsigned*)(vhT + (size_t)d * NKPAD + mb + sub * 32 + 2 * i) = lo | (hi << 16);
        }
    }
}

// ---------- Fused attention v12: depth-2 W/vis prefetch + setprio; LDS 37888 ----------
template<int USEBITS>
__global__ __launch_bounds__(256, 3) void attn_kernel_t(
    const unsigned short* __restrict__ qh, const unsigned short* __restrict__ kh,
    const unsigned short* __restrict__ vhT,
    const float* __restrict__ Wl, const int* __restrict__ vis,
    const unsigned* __restrict__ vbits,
    unsigned* __restrict__ OpartU, float* __restrict__ lpart) {
    __shared__ short Kl[2][32 * 136];   // K chunk [k][d] pad 136 -> 17408 B
    __shared__ short Vl[2][128 * VROW]; // V^T chunk [d][k] pad 40 -> 20480 B ; total 37888
    int bid = blockIdx.x;
    int split = bid % SPLITS, qt = bid / SPLITS;
    int t = threadIdx.x, wave = t >> 6, lane = t & 63;
    int l15 = lane & 15, quad = lane >> 4;
    int qb = qt * 64 + wave * 16;
    int k00 = split * (CPS * 32);
    int cmax = (NK - k00) >> 5; if (cmax > CPS) cmax = CPS;  // last split: 9

    // Q fragments (loop-invariant), B-operand layout
    short8 qB[4];
    #pragma unroll
    for (int h = 0; h < 4; h++)
        qB[h] = *(const short8*)(qh + (size_t)(qb + l15) * D + h * 32 + quad * 8);

    // staging assignment: K: thread -> row kr, 2x16B segs; V: row vd, 2x16B segs
    int kr = t >> 3, ks = (t & 7) * 2;
    int vd = t >> 1, vs = (t & 1) * 2;
    const uint4* ksrc = (const uint4*)(kh + (size_t)(k00 + kr) * D + ks * 8);
    const uint4* vsrc = (const uint4*)(vhT + (size_t)vd * NKPAD + k00 + vs * 8);
    short* kdst = &Kl[0][kr * 136 + ks * 8];
    short* vdst = &Vl[0][vd * VROW + vs * 8];

    // W/vis per lane: q = qb+l15, k = quad*4..+3 (+16)
    int wrow = qb + l15; if (wrow >= Q) wrow = Q - 1;
    const float* wp = Wl + (size_t)wrow * NK + k00 + quad * 4;
    const int*   vp = vis + (size_t)wrow * NK + k00 + quad * 4;
    const unsigned* vbp = vbits + (size_t)wrow * VBW + split * CPS;

    // shuffle indices for the P C->B transform (loop-invariant; verified round-3)
    int idxA = l15 + ((quad & 1) << 5);
    int idxB = idxA + 16;
    bool hiK = (quad >= 2);

    const floatx4 zf = {0.f, 0.f, 0.f, 0.f};
    floatx4 O[4][2];
    float lacc[4];
    #pragma unroll
    for (int h = 0; h < 4; h++) { O[h][0] = zf; O[h][1] = zf; lacc[h] = 0.f; }

    // prologue: chunk 0 K/V; W/vis depth-2 (chunks 0 and 1)
    uint4 ka = ksrc[0], kb2 = ksrc[1];
    uint4 va = vsrc[0], vb2 = vsrc[1];
    floatx4 wc0 = *(const floatx4*)wp;
    floatx4 wc1 = *(const floatx4*)(wp + 16);
    floatx4 wn0, wn1;
    intx4 vc0, vc1;
    unsigned vbc = 0, vbn = 0;
    if constexpr (USEBITS) {
        vbc = vbp[0];
        // cmax >= 9 always, so chunk 1 exists
        wn0 = *(const floatx4*)(wp + 32);
        wn1 = *(const floatx4*)(wp + 48);
        vbn = vbp[1];
    } else {
        vc0 = *(const intx4*)vp;
        vc1 = *(const intx4*)(vp + 16);
    }
    *(uint4*)kdst = ka;       *(uint4*)(kdst + 8) = kb2;
    *(uint4*)vdst = va;       *(uint4*)(vdst + 8) = vb2;

    #pragma unroll 1
    for (int c = 0; c < cmax; c++) {
        __syncthreads();
        int buf = c & 1;
        uint4 nka, nkb, nva, nvb;
        floatx4 w20, w21; intx4 vn0, vn1;
        unsigned vb2n = 0;
        if (c + 1 < cmax) {
            const uint4* ks2 = ksrc + (size_t)(c + 1) * 512;
            const uint4* vs2 = vsrc + (size_t)(c + 1) * 4;
            nka = ks2[0]; nkb = ks2[1];
            nva = vs2[0]; nvb = vs2[1];
        }
        if constexpr (USEBITS) {
            if (c + 2 < cmax) {
                w20 = *(const floatx4*)(wp + (c + 2) * 32);
                w21 = *(const floatx4*)(wp + (c + 2) * 32 + 16);
                vb2n = vbp[c + 2];
            }
        } else {
            if (c + 1 < cmax) {
                wn0 = *(const floatx4*)(wp + (c + 1) * 32);
                wn1 = *(const floatx4*)(wp + (c + 1) * 32 + 16);
                vn0 = *(const intx4*)(vp + (c + 1) * 32);
                vn1 = *(const intx4*)(vp + (c + 1) * 32 + 16);
            }
        }
        float a2[8], b2[8];
        if constexpr (USEBITS) {
            unsigned bq = vbc >> (quad * 4);
            #pragma unroll
            for (int r = 0; r < 4; r++) {
                bool m0 = (bq >> r) & 1u;
                bool m1 = (bq >> (16 + r)) & 1u;
                a2[r]     = m0 ? wc0[r] : 0.f;
                b2[r]     = m0 ? 0.f : wc0[r] * NEGBIG;
                a2[4 + r] = m1 ? wc1[r] : 0.f;
                b2[4 + r] = m1 ? 0.f : wc1[r] * NEGBIG;
            }
        } else {
            #pragma unroll
            for (int r = 0; r < 4; r++) {
                a2[r]     = vc0[r] ? wc0[r] : 0.f;
                b2[r]     = vc0[r] ? 0.f : wc0[r] * NEGBIG;
                a2[4 + r] = vc1[r] ? wc1[r] : 0.f;
                b2[4 + r] = vc1[r] ? 0.f : wc1[r] * NEGBIG;
            }
        }
        const short* Kb = Kl[buf];
        const short* Vb = Vl[buf];
        __builtin_amdgcn_s_setprio(1);
        #pragma unroll
        for (int h = 0; h < 4; h++) {
            short8 kA0 = *(const short8*)(Kb + l15 * 136 + h * 32 + quad * 8);
            short8 kA1 = *(const short8*)(Kb + (16 + l15) * 136 + h * 32 + quad * 8);
            floatx4 S0 = __builtin_amdgcn_mfma_f32_16x16x32_bf16(kA0, qB[h], zf, 0, 0, 0);
            floatx4 S1 = __builtin_amdgcn_mfma_f32_16x16x32_bf16(kA1, qB[h], zf, 0, 0, 0);
            float p0[4], p1[4];
            #pragma unroll
            for (int r = 0; r < 4; r++) {
                p0[r] = exp2f(S0[r] * a2[r] + b2[r]);
                p1[r] = exp2f(S1[r] * a2[4 + r] + b2[4 + r]);
                lacc[h] += p0[r] + p1[r];
            }
            // P C->B transform in-register: 4 cvt_pk + 8 bpermute + 4 selects.
            unsigned u0 = cvtpk(p0[0], p0[1]);
            unsigned u1 = cvtpk(p0[2], p0[3]);
            unsigned u2 = cvtpk(p1[0], p1[1]);
            unsigned u3 = cvtpk(p1[2], p1[3]);
            unsigned s0A = __shfl(u0, idxA, 64), s2A = __shfl(u2, idxA, 64);
            unsigned s1A = __shfl(u1, idxA, 64), s3A = __shfl(u3, idxA, 64);
            unsigned s0B = __shfl(u0, idxB, 64), s2B = __shfl(u2, idxB, 64);
            unsigned s1B = __shfl(u1, idxB, 64), s3B = __shfl(u3, idxB, 64);
            union { unsigned u[4]; short8 s8; } pb;
            pb.u[0] = hiK ? s2A : s0A;
            pb.u[1] = hiK ? s3A : s1A;
            pb.u[2] = hiK ? s2B : s0B;
            pb.u[3] = hiK ? s3B : s1B;
            short8 vA0 = *(const short8*)(Vb + (h * 32 + l15) * VROW + quad * 8);
            short8 vA1 = *(const short8*)(Vb + (h * 32 + 16 + l15) * VROW + quad * 8);
            O[h][0] = __builtin_amdgcn_mfma_f32_16x16x32_bf16(vA0, pb.s8, O[h][0], 0, 0, 0);
            O[h][1] = __builtin_amdgcn_mfma_f32_16x16x32_bf16(vA1, pb.s8, O[h][1], 0, 0, 0);
        }
        __builtin_amdgcn_s_setprio(0);
        if (c + 1 < cmax) {
            short* kd = buf ? kdst : (kdst + 32 * 136);
            short* vd2 = buf ? vdst : (vdst + 128 * VROW);
            *(uint4*)kd = nka;       *(uint4*)(kd + 8) = nkb;
            *(uint4*)vd2 = nva;      *(uint4*)(vd2 + 8) = nvb;
        }
        if constexpr (USEBITS) {
            wc0 = wn0; wc1 = wn1; vbc = vbn;
            if (c + 2 < cmax) { wn0 = w20; wn1 = w21; vbn = vb2n; }
        } else {
            if (c + 1 < cmax) { wc0 = wn0; wc1 = wn1; vc0 = vn0; vc1 = vn1; }
        }
    }

    int row = qb + l15;
    #pragma unroll
    for (int h = 0; h < 4; h++) {
        float lv = lacc[h];
        lv += __shfl_xor(lv, 16, 64);
        lv += __shfl_xor(lv, 32, 64);
        if (quad == 0) lpart[(size_t)split * LPS + row * 4 + h] = lv;
        #pragma unroll
        for (int tl = 0; tl < 2; tl++) {
            uint2 o2;
            o2.x = cvtpk(O[h][tl][0], O[h][tl][1]);
            o2.y = cvtpk(O[h][tl][2], O[h][tl][3]);
            *(uint2*)(OpartU + (size_t)split * OPS + ((size_t)row * 4 + h) * 16 + tl * 8 + quad * 2) = o2;
        }
    }
}

// ---------- split-combine: wide-parallel reduction of Opart -> A1 (bf16 [2560][128]) ----------
__global__ __launch_bounds__(128) void combine_kernel(
    const unsigned* __restrict__ Opart, const float* __restrict__ lpart,
    unsigned* __restrict__ A1u) {
    int tid = blockIdx.x * 128 + threadIdx.x;  // 320 blocks * 128 = 40960 units
    int sl = tid & 3, he = (tid >> 2) & 3, grow = tid >> 4;
    float lsum = 0.f;
    #pragma unroll 5
    for (int sp = 0; sp < SPLITS; sp++) lsum += lpart[(size_t)sp * LPS + grow * 4 + he];
    float inv = 1.0f / fmaxf(lsum, 1e-30f);
    size_t base = ((size_t)grow * 4 + he) * 16 + sl * 4;
    float a0 = 0.f, a1 = 0.f, a2 = 0.f, a3 = 0.f, a4 = 0.f, a5 = 0.f, a6 = 0.f, a7 = 0.f;
    #pragma unroll 5
    for (int sp = 0; sp < SPLITS; sp++) {
        uint4 u = *(const uint4*)(Opart + (size_t)sp * OPS + base);
        a0 += bflo(u.x); a1 += bfhi(u.x);
        a2 += bflo(u.y); a3 += bfhi(u.y);
        a4 += bflo(u.z); a5 += bfhi(u.z);
        a6 += bflo(u.w); a7 += bfhi(u.w);
    }
    uint4 o;
    o.x = pack2bf(a0 * inv, a1 * inv);
    o.y = pack2bf(a2 * inv, a3 * inv);
    o.z = pack2bf(a4 * inv, a5 * inv);
    o.w = pack2bf(a6 * inv, a7 * inv);
    *(uint4*)(A1u + (size_t)grow * 64 + he * 16 + sl * 4) = o;
}

// ---------- MLP epilogue (pure GEMM; A1 read from global) ----------
__global__ __launch_bounds__(256) void mlp_kernel(
    const unsigned short* __restrict__ A1,
    const unsigned short* __restrict__ wpT,
    const float* __restrict__ bp, const float* __restrict__ skip,
    const float* __restrict__ pre_w, const float* __restrict__ pre_b,
    const unsigned short* __restrict__ w1T, const float* __restrict__ b1,
    const unsigned short* __restrict__ w2T, const float* __restrict__ b2,
    const float* __restrict__ post_w, const float* __restrict__ post_b,
    float* __restrict__ out) {
    __shared__ __align__(16) char smem[51200];
    short* Z1 = (short*)smem;              // [64][136]
    short* H1 = (short*)(smem + 17408);    // [64][264]
    float* Zout = (float*)smem;            // [128][65] overlay after barrier

    int qb = blockIdx.x * 64;
    int t = threadIdx.x, wave = t >> 6, lane = t & 63;
    int l15 = lane & 15, quad = lane >> 4;
    int m0 = wave * 16;

    // G1: Z = A1 @ wp
    floatx4 z[8];
    #pragma unroll
    for (int i = 0; i < 8; i++) z[i] = (floatx4){0.f, 0.f, 0.f, 0.f};
    #pragma unroll
    for (int kf = 0; kf < 4; kf++) {
        short8 A = *(const short8*)(A1 + (size_t)(qb + m0 + l15) * 128 + kf * 32 + quad * 8);
        #pragma unroll
        for (int nt = 0; nt < 8; nt++) {
            short8 Bv = *(const short8*)(wpT + (nt * 16 + l15) * D + kf * 32 + quad * 8);
            z[nt] = __builtin_amdgcn_mfma_f32_16x16x32_bf16(A, Bv, z[nt], 0, 0, 0);
        }
    }
    float Zv[8][4];
    #pragma unroll
    for (int nt = 0; nt < 8; nt++) {
        int n = nt * 16 + l15;
        float bb = bp[n];
        #pragma unroll
        for (int r = 0; r < 4; r++) {
            int q = qb + m0 + quad * 4 + r;
            int qc = q < Q ? q : (Q - 1);
            Zv[nt][r] = z[nt][r] + bb + skip[n * Q + qc];
        }
    }
    // pre-LN
    float Zn[8][4];
    {
        #pragma unroll
        for (int r = 0; r < 4; r++) {
            float s1 = 0.f, s2 = 0.f;
            #pragma unroll
            for (int nt = 0; nt < 8; nt++) { s1 += Zv[nt][r]; s2 += Zv[nt][r] * Zv[nt][r]; }
            #pragma unroll
            for (int m = 1; m <= 8; m <<= 1) { s1 += __shfl_xor(s1, m, 64); s2 += __shfl_xor(s2, m, 64); }
            float mean = s1 * (1.0f / 128.0f);
            float var = s2 * (1.0f / 128.0f) - mean * mean;
            float rstd = rsqrtf(var + 1e-5f);
            #pragma unroll
            for (int nt = 0; nt < 8; nt++) Zn[nt][r] = (Zv[nt][r] - mean) * rstd;
        }
        #pragma unroll
        for (int nt = 0; nt < 8; nt++) {
            int n = nt * 16 + l15;
            float g = pre_w[n], be = pre_b[n];
            #pragma unroll
            for (int r = 0; r < 4; r++) {
                Zn[nt][r] = Zn[nt][r] * g + be;
                Z1[(m0 + quad * 4 + r) * 136 + n] = (short)f2bf(Zn[nt][r]);
            }
        }
    }
    // G2: H = gelu(Z1 @ w1 + b1)
    {
        floatx4 h2[16];
        #pragma unroll
        for (int i = 0; i < 16; i++) h2[i] = (floatx4){0.f, 0.f, 0.f, 0.f};
        #pragma unroll
        for (int kf = 0; kf < 4; kf++) {
            short8 A = *(const short8*)(Z1 + (m0 + l15) * 136 + kf * 32 + quad * 8);
            #pragma unroll
            for (int nt = 0; nt < 16; nt++) {
                short8 Bv = *(const short8*)(w1T + (nt * 16 + l15) * D + kf * 32 + quad * 8);
                h2[nt] = __builtin_amdgcn_mfma_f32_16x16x32_bf16(A, Bv, h2[nt], 0, 0, 0);
            }
        }
        #pragma unroll
        for (int nt = 0; nt < 16; nt++) {
            int n = nt * 16 + l15;
            float bb = b1[n];
            #pragma unroll
            for (int r = 0; r < 4; r++) {
                float x = h2[nt][r] + bb;
                float gl = 0.5f * x * (1.0f + erff(x * 0.70710678118654752f));
                H1[(m0 + quad * 4 + r) * 264 + n] = (short)f2bf(gl);
            }
        }
    }
    // G3: R = H1 @ w2 + b2; Z2 = Zn + R
    floatx4 o3[8];
    #pragma unroll
    for (int i = 0; i < 8; i++) o3[i] = (floatx4){0.f, 0.f, 0.f, 0.f};
    #pragma unroll
    for (int kf = 0; kf < 8; kf++) {
        short8 A = *(const short8*)(H1 + (m0 + l15) * 264 + kf * 32 + quad * 8);
        #pragma unroll
        for (int nt = 0; nt < 8; nt++) {
            short8 Bv = *(const short8*)(w2T + (nt * 16 + l15) * 256 + kf * 32 + quad * 8);
            o3[nt] = __builtin_amdgcn_mfma_f32_16x16x32_bf16(A, Bv, o3[nt], 0, 0, 0);
        }
    }
    float Z2[8][4];
    #pragma unroll
    for (int nt = 0; nt < 8; nt++) {
        int n = nt * 16 + l15;
        float bb = b2[n];
        #pragma unroll
        for (int r = 0; r < 4; r++) Z2[nt][r] = Zn[nt][r] + o3[nt][r] + bb;
    }
    // post-LN
    float Zo[8][4];
    {
        #pragma unroll
        for (int r = 0; r < 4; r++) {
            float s1 = 0.f, s2 = 0.f;
            #pragma unroll
            for (int nt = 0; nt < 8; nt++) { s1 += Z2[nt][r]; s2 += Z2[nt][r] * Z2[nt][r]; }
            #pragma unroll
            for (int m = 1; m <= 8; m <<= 1) { s1 += __shfl_xor(s1, m, 64); s2 += __shfl_xor(s2, m, 64); }
            float mean = s1 * (1.0f / 128.0f);
            float var = s2 * (1.0f / 128.0f) - mean * mean;
            float rstd = rsqrtf(var + 1e-5f);
            #pragma unroll
            for (int nt = 0; nt < 8; nt++) Zo[nt][r] = (Z2[nt][r] - mean) * rstd;
        }
        #pragma unroll
        for (int nt = 0; nt < 8; nt++) {
            int n = nt * 16 + l15;
            float g = post_w[n], be = post_b[n];
            #pragma unroll
            for (int r = 0; r < 4; r++) Zo[nt][r] = Zo[nt][r] * g + be;
        }
    }
    __syncthreads();
    #pragma unroll
    for (int nt = 0; nt < 8; nt++)
        #pragma unroll
        for (int r = 0; r < 4; r++)
            Zout[(nt * 16 + l15) * 65 + m0 + quad * 4 + r] = Zo[nt][r];
    __syncthreads();
    {
        int pl = t & 63;
        int q = qb + pl;
        if (q < Q) {
            #pragma unroll
            for (int it = 0; it < 32; it++) {
                int n = it * 4 + (t >> 6);
                out[n * Q + q] = Zout[n * 65 + pl];
            }
        }
    }
}

extern "C" void kernel_launch(void* const* d_in, const int* in_sizes, int n_in,
                              void* d_out, int out_size, void* d_ws, size_t ws_size,
                              hipStream_t stream) {
    (void)in_sizes; (void)n_in; (void)out_size;
    const float* q      = (const float*)d_in[0];
    const float* k      = (const float*)d_in[1];
    const float* v      = (const float*)d_in[2];
    const float* Wl     = (const float*)d_in[3];
    const int*   vis    = (const int*)  d_in[4];
    const float* skip   = (const float*)d_in[5];
    const float* qn_w   = (const float*)d_in[6];
    const float* qn_b   = (const float*)d_in[7];
    const float* kn_w   = (const float*)d_in[8];
    const float* kn_b   = (const float*)d_in[9];
    const float* vn_w   = (const float*)d_in[10];
    const float* vn_b   = (const float*)d_in[11];
    const float* pre_w  = (const float*)d_in[12];
    const float* pre_b  = (const float*)d_in[13];
    const float* post_w = (const float*)d_in[14];
    const float* post_b = (const float*)d_in[15];
    const float* wq     = (const float*)d_in[16];
    const float* bq     = (const float*)d_in[17];
    const float* wk     = (const float*)d_in[18];
    const float* bk     = (const float*)d_in[19];
    const float* wv     = (const float*)d_in[20];
    const float* bv     = (const float*)d_in[21];
    const float* wp     = (const float*)d_in[22];
    const float* bp     = (const float*)d_in[23];
    const float* w1     = (const float*)d_in[24];
    const float* b1     = (const float*)d_in[25];
    const float* w2     = (const float*)d_in[26];
    const float* b2     = (const float*)d_in[27];
    float* out = (float*)d_out;

    char* ws = (char*)d_ws;
    unsigned short* xq  = (unsigned short*)(ws + 0);          //  2560*128 bf16 (reused as A1 post-attn)
    unsigned short* xk  = (unsigned short*)(ws + 655360);     // 10112*128 bf16
    unsigned short* xv  = (unsigned short*)(ws + 3244032);
    unsigned short* qh  = (unsigned short*)(ws + 5832704);
    unsigned short* kh  = (unsigned short*)(ws + 6488064);
    unsigned short* vhT = (unsigned short*)(ws + 9076736);    // [128][10112] bf16
    unsigned short* wqT = (unsigned short*)(ws + 11665408);
    unsigned short* wkT = (unsigned short*)(ws + 11698176);
    unsigned short* wvT = (unsigned short*)(ws + 11730944);
    unsigned short* wpT = (unsigned short*)(ws + 11763712);
    unsigned short* w1T = (unsigned short*)(ws + 11796480);
    unsigned short* w2T = (unsigned short*)(ws + 11862016);
    unsigned* OpartU    = (unsigned*)(ws + 11927552);         // 19*OPS u32 (padded stride)
    float* lpart        = (float*)(ws + 34874112);            // 19*LPS f32
    unsigned* vbits     = (unsigned*)(ws + 36316672);         // 2500*320 u32 = 3.2 MB
    // A1 [2560][128] bf16 reuses the xq region (dead after proj) — no ws growth
    unsigned* A1u       = (unsigned*)(ws + 0);
    // high-water: ~39.6 MB (packed path) / ~36.3 MB (fallback)

    const bool usebits = (ws_size == 0) || (ws_size >= 39520000ull);

    prep_kernel<<<dim3(usebits ? 3727 : 1227), dim3(256), 0, stream>>>(
        q, k, v, qn_w, qn_b, kn_w, kn_b, vn_w, vn_b, xq, xk, xv,
        wq, wk, wv, wp, w1, w2, wqT, wkT, wvT, wpT, w1T, w2T, vis, vbits);
    proj_kernel<<<dim3(356), dim3(256), 0, stream>>>(xq, xk, xv, wqT, wkT, wvT, bq, bk, bv,
                                                     qh, kh, vhT);
    if (usebits)
        attn_kernel_t<1><<<dim3(40 * SPLITS), dim3(256), 0, stream>>>(
            qh, kh, vhT, Wl, vis, vbits, OpartU, lpart);
    else
        attn_kernel_t<0><<<dim3(40 * SPLITS), dim3(256), 0, stream>>>(
            qh, kh, vhT, Wl, vis, vbits, OpartU, lpart);
    combine_kernel<<<dim3(320), dim3(128), 0, stream>>>(OpartU, lpart, A1u);
    mlp_kernel<<<dim3(40), dim3(256), 0, stream>>>((const unsigned short*)A1u, wpT, bp, skip,
                                                   pre_w, pre_b, w1T, b1, w2T, b2,
                                                   post_w, post_b, out);
}

// Round 8
// 358.473 us; speedup vs baseline: 1.0270x; 1.0049x over previous
//
#include <hip/hip_runtime.h>
#include <hip/hip_bf16.h>
#include <math.h>

typedef short short8 __attribute__((ext_vector_type(8)));
typedef float floatx4 __attribute__((ext_vector_type(4)));
typedef int   intx4  __attribute__((ext_vector_type(4)));

#define D 128
#define Q 2500
#define QPAD 2560
#define NK 10080
#define NKPAD 10112
#define SPLITS 19
#define CPS 17   // ceil(315/19)=17 chunks of 32; last split has 9
// padded strides (avoid 4096B channel alignment)
#define OPS 163904   // u32 per split for OpartU
#define LPS 10304    // f32 per split for lpart
// vis bitmask: 315 words/row used, stride 320 u32 (1280 B)
#define VBW 320
// V LDS row pad: 40 shorts (80B, 16B-aligned stride)
#define VROW 40
// 1/sqrt(32) * log2(e)
#define QSCALE 0.25501268426834347f
#define NEGBIG -3.0e38f

// Workgroup barrier WITHOUT vmcnt drain: only LDS ops must be complete/visible
// at the barrier (ds_writes to next buf + ds_reads of current buf). Global
// prefetch loads (W/vis/K/V) keep counted vmcnt at their USE, so they stay in
// flight across chunk boundaries (T4; the __syncthreads() vmcnt(0) drain was
// the round-7 limiter).
#define LDS_BARRIER() asm volatile("s_waitcnt lgkmcnt(0)\n\ts_barrier" ::: "memory")

__device__ __forceinline__ unsigned short f2bf(float f) {
    unsigned u = __float_as_uint(f);
    unsigned r = (u + 0x7fffu + ((u >> 16) & 1u)) >> 16;
    return (unsigned short)r;
}
__device__ __forceinline__ unsigned pack2bf(float lo, float hi) {
    unsigned u0 = __float_as_uint(lo) + 0x8000u;
    unsigned u1 = __float_as_uint(hi) + 0x8000u;
    return (u0 >> 16) | (u1 & 0xffff0000u);
}
// HW packed f32->bf16 (RNE), lo -> [15:0], hi -> [31:16]
__device__ __forceinline__ unsigned cvtpk(float lo, float hi) {
    unsigned r;
    asm("v_cvt_pk_bf16_f32 %0, %1, %2" : "=v"(r) : "v"(lo), "v"(hi));
    return r;
}
__device__ __forceinline__ float bflo(unsigned u) { return __uint_as_float(u << 16); }
__device__ __forceinline__ float bfhi(unsigned u) { return __uint_as_float(u & 0xffff0000u); }

// ---------- prep: LayerNorm tiles + weight convert + vis bit-pack (fused) ----------
__global__ __launch_bounds__(256) void prep_kernel(
    const float* __restrict__ qi, const float* __restrict__ ki, const float* __restrict__ vi,
    const float* __restrict__ qw, const float* __restrict__ qb_,
    const float* __restrict__ kw, const float* __restrict__ kb,
    const float* __restrict__ vw, const float* __restrict__ vb,
    unsigned short* __restrict__ xq, unsigned short* __restrict__ xk,
    unsigned short* __restrict__ xv,
    const float* __restrict__ wq, const float* __restrict__ wk,
    const float* __restrict__ wv, const float* __restrict__ wp,
    const float* __restrict__ w1, const float* __restrict__ w2,
    unsigned short* __restrict__ wqT, unsigned short* __restrict__ wkT,
    unsigned short* __restrict__ wvT, unsigned short* __restrict__ wpT,
    unsigned short* __restrict__ w1T, unsigned short* __restrict__ w2T,
    const int* __restrict__ vis, unsigned* __restrict__ vbits) {
    int bid = blockIdx.x, t = threadIdx.x;
    if (bid >= 1227) {
        // vis bit-pack: one row per block
        int row = bid - 1227;
        const int* src = vis + (size_t)row * NK;
        #pragma unroll 2
        for (int w = t; w < 315; w += 256) {
            unsigned bits = 0;
            const intx4* p = (const intx4*)(src + w * 32);
            #pragma unroll
            for (int g = 0; g < 8; g++) {
                intx4 v = p[g];
                #pragma unroll
                for (int j = 0; j < 4; j++) bits |= (v[j] ? 1u : 0u) << (g * 4 + j);
            }
            vbits[(size_t)row * VBW + w] = bits;
        }
        return;
    }
    if (bid >= 715) {
        int idx = (bid - 715) * 256 + t;  // 131072 total
        if (idx < 49152) {
            int m = idx >> 14;
            int local = idx & 16383;
            int n = local >> 7, kk = local & 127;
            const float* w = (m == 0) ? wq : ((m == 1) ? wk : wv);
            unsigned short* o = (m == 0) ? wqT : ((m == 1) ? wkT : wvT);
            o[local] = f2bf(w[kk * 128 + n]);
        } else if (idx < 65536) {
            int local = idx - 49152;
            int n = local >> 7, kk = local & 127;
            wpT[local] = f2bf(wp[kk * 128 + n]);
        } else if (idx < 98304) {
            int local = idx - 65536;
            int n = local >> 7, kk = local & 127;
            w1T[local] = f2bf(w1[kk * 256 + n]);
        } else {
            int local = idx - 98304;
            int n = local >> 8, kk = local & 255;
            w2T[local] = f2bf(w2[kk * 128 + n]);
        }
        return;
    }
    __shared__ float lds2[32 * 132];
    const float* src; unsigned short* dst; const float *g, *b;
    int S, valid;
    if (bid < 79) {
        int p0 = bid * 32;
        src = qi + p0; S = Q; dst = xq + p0 * D; g = qw; b = qb_;
        valid = Q - p0; if (valid > 32) valid = 32;
    } else if (bid < 397) {
        int tt = bid - 79;
        int n = tt / 53, tile = tt - n * 53, r = tile * 32;
        src = ki + (size_t)(n * 128) * 1680 + r; S = 1680;
        dst = xk + (n * 1680 + r) * D; g = kw; b = kb;
        valid = 1680 - r; if (valid > 32) valid = 32;
    } else {
        int tt = bid - 397;
        int n = tt / 53, tile = tt - n * 53, r = tile * 32;
        src = vi + (size_t)(n * 128) * 1680 + r; S = 1680;
        dst = xv + (n * 1680 + r) * D; g = vw; b = vb;
        valid = 1680 - r; if (valid > 32) valid = 32;
    }
    #pragma unroll
    for (int pass = 0; pass < 4; pass++) {
        int s = pass * 256 + t;
        int d = s >> 3, ps = s & 7;
        floatx4 val = {0.f, 0.f, 0.f, 0.f};
        if (ps * 4 < valid) val = *(const floatx4*)(src + (size_t)d * S + ps * 4);
        #pragma unroll
        for (int j = 0; j < 4; j++) lds2[(ps * 4 + j) * 132 + d] = val[j];
    }
    __syncthreads();
    int lane = t & 63, wvx = t >> 6;
    int pos = wvx * 8 + (lane >> 3), l7 = lane & 7;
    floatx4 x4[4];
    #pragma unroll
    for (int k = 0; k < 4; k++) x4[k] = *(const floatx4*)(&lds2[pos * 132 + l7 * 16 + k * 4]);
    float s = 0.f, ss = 0.f;
    #pragma unroll
    for (int k = 0; k < 4; k++)
        #pragma unroll
        for (int j = 0; j < 4; j++) { s += x4[k][j]; ss += x4[k][j] * x4[k][j]; }
    #pragma unroll
    for (int m = 1; m <= 4; m <<= 1) { s += __shfl_xor(s, m, 64); ss += __shfl_xor(ss, m, 64); }
    float mean = s * (1.0f / 128.0f);
    float var = ss * (1.0f / 128.0f) - mean * mean;
    float rstd = rsqrtf(var + 1e-5f);
    short8 o1, o2;
    #pragma unroll
    for (int k = 0; k < 4; k++) {
        floatx4 g4 = *(const floatx4*)(g + l7 * 16 + k * 4);
        floatx4 b4 = *(const floatx4*)(b + l7 * 16 + k * 4);
        #pragma unroll
        for (int j = 0; j < 4; j++) {
            float o = (x4[k][j] - mean) * rstd * g4[j] + b4[j];
            if (k < 2) o1[k * 4 + j] = (short)f2bf(o);
            else o2[(k - 2) * 4 + j] = (short)f2bf(o);
        }
    }
    if (pos < valid) {
        *(short8*)(dst + pos * D + l7 * 16) = o1;
        *(short8*)(dst + pos * D + l7 * 16 + 8) = o2;
    }
}

// ---------- Projection GEMM, vectorized weights; V written transposed ----------
__global__ __launch_bounds__(256) void proj_kernel(
    const unsigned short* __restrict__ xq, const unsigned short* __restrict__ xk,
    const unsigned short* __restrict__ xv,
    const unsigned short* __restrict__ wqT, const unsigned short* __restrict__ wkT,
    const unsigned short* __restrict__ wvT,
    const float* __restrict__ bq, const float* __restrict__ bk, const float* __restrict__ bv,
    unsigned short* __restrict__ qh, unsigned short* __restrict__ kh,
    unsigned short* __restrict__ vhT) {
    __shared__ short vlds[128 * 72];
    int bid = blockIdx.x;
    const unsigned short *src, *wT; const float* bias; int mb, mode; float scale;
    if (bid < 40)       { mode = 0; src = xq; wT = wqT; bias = bq; mb = bid * 64; scale = QSCALE; }
    else if (bid < 198) { mode = 1; src = xk; wT = wkT; bias = bk; mb = (bid - 40) * 64; scale = 1.0f; }
    else                { mode = 2; src = xv; wT = wvT; bias = bv; mb = (bid - 198) * 64; scale = 1.0f; }
    int t = threadIdx.x, wave = t >> 6, lane = t & 63;
    int l15 = lane & 15, quad = lane >> 4;
    int m0 = mb + wave * 16;
    floatx4 acc[8];
    #pragma unroll
    for (int i = 0; i < 8; i++) acc[i] = (floatx4){0.f, 0.f, 0.f, 0.f};
    #pragma unroll
    for (int kf = 0; kf < 4; kf++) {
        short8 A = *(const short8*)(src + (m0 + l15) * D + kf * 32 + quad * 8);
        #pragma unroll
        for (int nt = 0; nt < 8; nt++) {
            short8 Bv = *(const short8*)(wT + (nt * 16 + l15) * D + kf * 32 + quad * 8);
            acc[nt] = __builtin_amdgcn_mfma_f32_16x16x32_bf16(A, Bv, acc[nt], 0, 0, 0);
        }
    }
    if (mode != 2) {
        unsigned short* dst = (mode == 0) ? qh : kh;
        #pragma unroll
        for (int nt = 0; nt < 8; nt++) {
            float bb = bias[nt * 16 + l15];
            #pragma unroll
            for (int r = 0; r < 4; r++)
                dst[(m0 + quad * 4 + r) * D + nt * 16 + l15] = f2bf((acc[nt][r] + bb) * scale);
        }
    } else {
        #pragma unroll
        for (int nt = 0; nt < 8; nt++) {
            float bb = bias[nt * 16 + l15];
            #pragma unroll
            for (int r = 0; r < 4; r++)
                vlds[(nt * 16 + l15) * 72 + (wave * 16 + quad * 4 + r)] =
                    (short)f2bf(acc[nt][r] + bb);
        }
        __syncthreads();
        int pr = t & 31, dd = t >> 5;
        int sub = pr >> 4, i = pr & 15;
        #pragma unroll
        for (int pass = 0; pass < 16; pass++) {
            int d = pass * 8 + dd;
            unsigned lo = (unsigned short)vlds[d * 72 + sub * 32 + i];
            unsigned hi = (unsigned short)vlds[d * 72 + sub * 32 + 16 + i];
            *(unsigned*)(vhT + (size_t)d * NKPAD + mb + sub * 32 + 2 * i) = lo | (hi << 16);
        }
    }
}

// ---------- Fused attention v13: v12 + non-draining LDS barrier (counted vmcnt, T4) ----------
template<int USEBITS>
__global__ __launch_bounds__(256, 3) void attn_kernel_t(
    const unsigned short* __restrict__ qh, const unsigned short* __restrict__ kh,
    const unsigned short* __restrict__ vhT,
    const float* __restrict__ Wl, const int* __restrict__ vis,
    const unsigned* __restrict__ vbits,
    unsigned* __restrict__ OpartU, float* __restrict__ lpart) {
    __shared__ short Kl[2][32 * 136];   // K chunk [k][d] pad 136 -> 17408 B
    __shared__ short Vl[2][128 * VROW]; // V^T chunk [d][k] pad 40 -> 20480 B ; total 37888
    int bid = blockIdx.x;
    int split = bid % SPLITS, qt = bid / SPLITS;
    int t = threadIdx.x, wave = t >> 6, lane = t & 63;
    int l15 = lane & 15, quad = lane >> 4;
    int qb = qt * 64 + wave * 16;
    int k00 = split * (CPS * 32);
    int cmax = (NK - k00) >> 5; if (cmax > CPS) cmax = CPS;  // last split: 9

    // Q fragments (loop-invariant), B-operand layout
    short8 qB[4];
    #pragma unroll
    for (int h = 0; h < 4; h++)
        qB[h] = *(const short8*)(qh + (size_t)(qb + l15) * D + h * 32 + quad * 8);

    // staging assignment: K: thread -> row kr, 2x16B segs; V: row vd, 2x16B segs
    int kr = t >> 3, ks = (t & 7) * 2;
    int vd = t >> 1, vs = (t & 1) * 2;
    const uint4* ksrc = (const uint4*)(kh + (size_t)(k00 + kr) * D + ks * 8);
    const uint4* vsrc = (const uint4*)(vhT + (size_t)vd * NKPAD + k00 + vs * 8);
    short* kdst = &Kl[0][kr * 136 + ks * 8];
    short* vdst = &Vl[0][vd * VROW + vs * 8];

    // W/vis per lane: q = qb+l15, k = quad*4..+3 (+16)
    int wrow = qb + l15; if (wrow >= Q) wrow = Q - 1;
    const float* wp = Wl + (size_t)wrow * NK + k00 + quad * 4;
    const int*   vp = vis + (size_t)wrow * NK + k00 + quad * 4;
    const unsigned* vbp = vbits + (size_t)wrow * VBW + split * CPS;

    // shuffle indices for the P C->B transform (loop-invariant; verified round-3)
    int idxA = l15 + ((quad & 1) << 5);
    int idxB = idxA + 16;
    bool hiK = (quad >= 2);

    const floatx4 zf = {0.f, 0.f, 0.f, 0.f};
    floatx4 O[4][2];
    float lacc[4];
    #pragma unroll
    for (int h = 0; h < 4; h++) { O[h][0] = zf; O[h][1] = zf; lacc[h] = 0.f; }

    // prologue: chunk 0 K/V; W/vis depth-2 (chunks 0 and 1)
    uint4 ka = ksrc[0], kb2 = ksrc[1];
    uint4 va = vsrc[0], vb2 = vsrc[1];
    floatx4 wc0 = *(const floatx4*)wp;
    floatx4 wc1 = *(const floatx4*)(wp + 16);
    floatx4 wn0, wn1;
    intx4 vc0, vc1;
    unsigned vbc = 0, vbn = 0;
    if constexpr (USEBITS) {
        vbc = vbp[0];
        // cmax >= 9 always, so chunk 1 exists
        wn0 = *(const floatx4*)(wp + 32);
        wn1 = *(const floatx4*)(wp + 48);
        vbn = vbp[1];
    } else {
        vc0 = *(const intx4*)vp;
        vc1 = *(const intx4*)(vp + 16);
    }
    *(uint4*)kdst = ka;       *(uint4*)(kdst + 8) = kb2;
    *(uint4*)vdst = va;       *(uint4*)(vdst + 8) = vb2;

    #pragma unroll 1
    for (int c = 0; c < cmax; c++) {
        LDS_BARRIER();
        int buf = c & 1;
        uint4 nka, nkb, nva, nvb;
        floatx4 w20, w21; intx4 vn0, vn1;
        unsigned vb2n = 0;
        if (c + 1 < cmax) {
            const uint4* ks2 = ksrc + (size_t)(c + 1) * 512;
            const uint4* vs2 = vsrc + (size_t)(c + 1) * 4;
            nka = ks2[0]; nkb = ks2[1];
            nva = vs2[0]; nvb = vs2[1];
        }
        if constexpr (USEBITS) {
            if (c + 2 < cmax) {
                w20 = *(const floatx4*)(wp + (c + 2) * 32);
                w21 = *(const floatx4*)(wp + (c + 2) * 32 + 16);
                vb2n = vbp[c + 2];
            }
        } else {
            if (c + 1 < cmax) {
                wn0 = *(const floatx4*)(wp + (c + 1) * 32);
                wn1 = *(const floatx4*)(wp + (c + 1) * 32 + 16);
                vn0 = *(const intx4*)(vp + (c + 1) * 32);
                vn1 = *(const intx4*)(vp + (c + 1) * 32 + 16);
            }
        }
        float a2[8], b2[8];
        if constexpr (USEBITS) {
            unsigned bq = vbc >> (quad * 4);
            #pragma unroll
            for (int r = 0; r < 4; r++) {
                bool m0 = (bq >> r) & 1u;
                bool m1 = (bq >> (16 + r)) & 1u;
                a2[r]     = m0 ? wc0[r] : 0.f;
                b2[r]     = m0 ? 0.f : wc0[r] * NEGBIG;
                a2[4 + r] = m1 ? wc1[r] : 0.f;
                b2[4 + r] = m1 ? 0.f : wc1[r] * NEGBIG;
            }
        } else {
            #pragma unroll
            for (int r = 0; r < 4; r++) {
                a2[r]     = vc0[r] ? wc0[r] : 0.f;
                b2[r]     = vc0[r] ? 0.f : wc0[r] * NEGBIG;
                a2[4 + r] = vc1[r] ? wc1[r] : 0.f;
                b2[4 + r] = vc1[r] ? 0.f : wc1[r] * NEGBIG;
            }
        }
        const short* Kb = Kl[buf];
        const short* Vb = Vl[buf];
        __builtin_amdgcn_s_setprio(1);
        #pragma unroll
        for (int h = 0; h < 4; h++) {
            short8 kA0 = *(const short8*)(Kb + l15 * 136 + h * 32 + quad * 8);
            short8 kA1 = *(const short8*)(Kb + (16 + l15) * 136 + h * 32 + quad * 8);
            floatx4 S0 = __builtin_amdgcn_mfma_f32_16x16x32_bf16(kA0, qB[h], zf, 0, 0, 0);
            floatx4 S1 = __builtin_amdgcn_mfma_f32_16x16x32_bf16(kA1, qB[h], zf, 0, 0, 0);
            float p0[4], p1[4];
            #pragma unroll
            for (int r = 0; r < 4; r++) {
                p0[r] = exp2f(S0[r] * a2[r] + b2[r]);
                p1[r] = exp2f(S1[r] * a2[4 + r] + b2[4 + r]);
                lacc[h] += p0[r] + p1[r];
            }
            // P C->B transform in-register: 4 cvt_pk + 8 bpermute + 4 selects.
            unsigned u0 = cvtpk(p0[0], p0[1]);
            unsigned u1 = cvtpk(p0[2], p0[3]);
            unsigned u2 = cvtpk(p1[0], p1[1]);
            unsigned u3 = cvtpk(p1[2], p1[3]);
            unsigned s0A = __shfl(u0, idxA, 64), s2A = __shfl(u2, idxA, 64);
            unsigned s1A = __shfl(u1, idxA, 64), s3A = __shfl(u3, idxA, 64);
            unsigned s0B = __shfl(u0, idxB, 64), s2B = __shfl(u2, idxB, 64);
            unsigned s1B = __shfl(u1, idxB, 64), s3B = __shfl(u3, idxB, 64);
            union { unsigned u[4]; short8 s8; } pb;
            pb.u[0] = hiK ? s2A : s0A;
            pb.u[1] = hiK ? s3A : s1A;
            pb.u[2] = hiK ? s2B : s0B;
            pb.u[3] = hiK ? s3B : s1B;
            short8 vA0 = *(const short8*)(Vb + (h * 32 + l15) * VROW + quad * 8);
            short8 vA1 = *(const short8*)(Vb + (h * 32 + 16 + l15) * VROW + quad * 8);
            O[h][0] = __builtin_amdgcn_mfma_f32_16x16x32_bf16(vA0, pb.s8, O[h][0], 0, 0, 0);
            O[h][1] = __builtin_amdgcn_mfma_f32_16x16x32_bf16(vA1, pb.s8, O[h][1], 0, 0, 0);
        }
        __builtin_amdgcn_s_setprio(0);
        if (c + 1 < cmax) {
            short* kd = buf ? kdst : (kdst + 32 * 136);
            short* vd2 = buf ? vdst : (vdst + 128 * VROW);
            *(uint4*)kd = nka;       *(uint4*)(kd + 8) = nkb;
            *(uint4*)vd2 = nva;      *(uint4*)(vd2 + 8) = nvb;
        }
        if constexpr (USEBITS) {
            wc0 = wn0; wc1 = wn1; vbc = vbn;
            if (c + 2 < cmax) { wn0 = w20; wn1 = w21; vbn = vb2n; }
        } else {
            if (c + 1 < cmax) { wc0 = wn0; wc1 = wn1; vc0 = vn0; vc1 = vn1; }
        }
    }

    int row = qb + l15;
    #pragma unroll
    for (int h = 0; h < 4; h++) {
        float lv = lacc[h];
        lv += __shfl_xor(lv, 16, 64);
        lv += __shfl_xor(lv, 32, 64);
        if (quad == 0) lpart[(size_t)split * LPS + row * 4 + h] = lv;
        #pragma unroll
        for (int tl = 0; tl < 2; tl++) {
            uint2 o2;
            o2.x = cvtpk(O[h][tl][0], O[h][tl][1]);
            o2.y = cvtpk(O[h][tl][2], O[h][tl][3]);
            *(uint2*)(OpartU + (size_t)split * OPS + ((size_t)row * 4 + h) * 16 + tl * 8 + quad * 2) = o2;
        }
    }
}

// ---------- split-combine: wide-parallel reduction of Opart -> A1 (bf16 [2560][128]) ----------
__global__ __launch_bounds__(128) void combine_kernel(
    const unsigned* __restrict__ Opart, const float* __restrict__ lpart,
    unsigned* __restrict__ A1u) {
    int tid = blockIdx.x * 128 + threadIdx.x;  // 320 blocks * 128 = 40960 units
    int sl = tid & 3, he = (tid >> 2) & 3, grow = tid >> 4;
    float lsum = 0.f;
    #pragma unroll 5
    for (int sp = 0; sp < SPLITS; sp++) lsum += lpart[(size_t)sp * LPS + grow * 4 + he];
    float inv = 1.0f / fmaxf(lsum, 1e-30f);
    size_t base = ((size_t)grow * 4 + he) * 16 + sl * 4;
    float a0 = 0.f, a1 = 0.f, a2 = 0.f, a3 = 0.f, a4 = 0.f, a5 = 0.f, a6 = 0.f, a7 = 0.f;
    #pragma unroll 5
    for (int sp = 0; sp < SPLITS; sp++) {
        uint4 u = *(const uint4*)(Opart + (size_t)sp * OPS + base);
        a0 += bflo(u.x); a1 += bfhi(u.x);
        a2 += bflo(u.y); a3 += bfhi(u.y);
        a4 += bflo(u.z); a5 += bfhi(u.z);
        a6 += bflo(u.w); a7 += bfhi(u.w);
    }
    uint4 o;
    o.x = pack2bf(a0 * inv, a1 * inv);
    o.y = pack2bf(a2 * inv, a3 * inv);
    o.z = pack2bf(a4 * inv, a5 * inv);
    o.w = pack2bf(a6 * inv, a7 * inv);
    *(uint4*)(A1u + (size_t)grow * 64 + he * 16 + sl * 4) = o;
}

// ---------- MLP epilogue (pure GEMM; A1 read from global) ----------
__global__ __launch_bounds__(256) void mlp_kernel(
    const unsigned short* __restrict__ A1,
    const unsigned short* __restrict__ wpT,
    const float* __restrict__ bp, const float* __restrict__ skip,
    const float* __restrict__ pre_w, const float* __restrict__ pre_b,
    const unsigned short* __restrict__ w1T, const float* __restrict__ b1,
    const unsigned short* __restrict__ w2T, const float* __restrict__ b2,
    const float* __restrict__ post_w, const float* __restrict__ post_b,
    float* __restrict__ out) {
    __shared__ __align__(16) char smem[51200];
    short* Z1 = (short*)smem;              // [64][136]
    short* H1 = (short*)(smem + 17408);    // [64][264]
    float* Zout = (float*)smem;            // [128][65] overlay after barrier

    int qb = blockIdx.x * 64;
    int t = threadIdx.x, wave = t >> 6, lane = t & 63;
    int l15 = lane & 15, quad = lane >> 4;
    int m0 = wave * 16;

    // G1: Z = A1 @ wp
    floatx4 z[8];
    #pragma unroll
    for (int i = 0; i < 8; i++) z[i] = (floatx4){0.f, 0.f, 0.f, 0.f};
    #pragma unroll
    for (int kf = 0; kf < 4; kf++) {
        short8 A = *(const short8*)(A1 + (size_t)(qb + m0 + l15) * 128 + kf * 32 + quad * 8);
        #pragma unroll
        for (int nt = 0; nt < 8; nt++) {
            short8 Bv = *(const short8*)(wpT + (nt * 16 + l15) * D + kf * 32 + quad * 8);
            z[nt] = __builtin_amdgcn_mfma_f32_16x16x32_bf16(A, Bv, z[nt], 0, 0, 0);
        }
    }
    float Zv[8][4];
    #pragma unroll
    for (int nt = 0; nt < 8; nt++) {
        int n = nt * 16 + l15;
        float bb = bp[n];
        #pragma unroll
        for (int r = 0; r < 4; r++) {
            int q = qb + m0 + quad * 4 + r;
            int qc = q < Q ? q : (Q - 1);
            Zv[nt][r] = z[nt][r] + bb + skip[n * Q + qc];
        }
    }
    // pre-LN
    float Zn[8][4];
    {
        #pragma unroll
        for (int r = 0; r < 4; r++) {
            float s1 = 0.f, s2 = 0.f;
            #pragma unroll
            for (int nt = 0; nt < 8; nt++) { s1 += Zv[nt][r]; s2 += Zv[nt][r] * Zv[nt][r]; }
            #pragma unroll
            for (int m = 1; m <= 8; m <<= 1) { s1 += __shfl_xor(s1, m, 64); s2 += __shfl_xor(s2, m, 64); }
            float mean = s1 * (1.0f / 128.0f);
            float var = s2 * (1.0f / 128.0f) - mean * mean;
            float rstd = rsqrtf(var + 1e-5f);
            #pragma unroll
            for (int nt = 0; nt < 8; nt++) Zn[nt][r] = (Zv[nt][r] - mean) * rstd;
        }
        #pragma unroll
        for (int nt = 0; nt < 8; nt++) {
            int n = nt * 16 + l15;
            float g = pre_w[n], be = pre_b[n];
            #pragma unroll
            for (int r = 0; r < 4; r++) {
                Zn[nt][r] = Zn[nt][r] * g + be;
                Z1[(m0 + quad * 4 + r) * 136 + n] = (short)f2bf(Zn[nt][r]);
            }
        }
    }
    // G2: H = gelu(Z1 @ w1 + b1)
    {
        floatx4 h2[16];
        #pragma unroll
        for (int i = 0; i < 16; i++) h2[i] = (floatx4){0.f, 0.f, 0.f, 0.f};
        #pragma unroll
        for (int kf = 0; kf < 4; kf++) {
            short8 A = *(const short8*)(Z1 + (m0 + l15) * 136 + kf * 32 + quad * 8);
            #pragma unroll
            for (int nt = 0; nt < 16; nt++) {
                short8 Bv = *(const short8*)(w1T + (nt * 16 + l15) * D + kf * 32 + quad * 8);
                h2[nt] = __builtin_amdgcn_mfma_f32_16x16x32_bf16(A, Bv, h2[nt], 0, 0, 0);
            }
        }
        #pragma unroll
        for (int nt = 0; nt < 16; nt++) {
            int n = nt * 16 + l15;
            float bb = b1[n];
            #pragma unroll
            for (int r = 0; r < 4; r++) {
                float x = h2[nt][r] + bb;
                float gl = 0.5f * x * (1.0f + erff(x * 0.70710678118654752f));
                H1[(m0 + quad * 4 + r) * 264 + n] = (short)f2bf(gl);
            }
        }
    }
    // G3: R = H1 @ w2 + b2; Z2 = Zn + R
    floatx4 o3[8];
    #pragma unroll
    for (int i = 0; i < 8; i++) o3[i] = (floatx4){0.f, 0.f, 0.f, 0.f};
    #pragma unroll
    for (int kf = 0; kf < 8; kf++) {
        short8 A = *(const short8*)(H1 + (m0 + l15) * 264 + kf * 32 + quad * 8);
        #pragma unroll
        for (int nt = 0; nt < 8; nt++) {
            short8 Bv = *(const short8*)(w2T + (nt * 16 + l15) * 256 + kf * 32 + quad * 8);
            o3[nt] = __builtin_amdgcn_mfma_f32_16x16x32_bf16(A, Bv, o3[nt], 0, 0, 0);
        }
    }
    float Z2[8][4];
    #pragma unroll
    for (int nt = 0; nt < 8; nt++) {
        int n = nt * 16 + l15;
        float bb = b2[n];
        #pragma unroll
        for (int r = 0; r < 4; r++) Z2[nt][r] = Zn[nt][r] + o3[nt][r] + bb;
    }
    // post-LN
    float Zo[8][4];
    {
        #pragma unroll
        for (int r = 0; r < 4; r++) {
            float s1 = 0.f, s2 = 0.f;
            #pragma unroll
            for (int nt = 0; nt < 8; nt++) { s1 += Z2[nt][r]; s2 += Z2[nt][r] * Z2[nt][r]; }
            #pragma unroll
            for (int m = 1; m <= 8; m <<= 1) { s1 += __shfl_xor(s1, m, 64); s2 += __shfl_xor(s2, m, 64); }
            float mean = s1 * (1.0f / 128.0f);
            float var = s2 * (1.0f / 128.0f) - mean * mean;
            float rstd = rsqrtf(var + 1e-5f);
            #pragma unroll
            for (int nt = 0; nt < 8; nt++) Zo[nt][r] = (Z2[nt][r] - mean) * rstd;
        }
        #pragma unroll
        for (int nt = 0; nt < 8; nt++) {
            int n = nt * 16 + l15;
            float g = post_w[n], be = post_b[n];
            #pragma unroll
            for (int r = 0; r < 4; r++) Zo[nt][r] = Zo[nt][r] * g + be;
        }
    }
    __syncthreads();
    #pragma unroll
    for (int nt = 0; nt < 8; nt++)
        #pragma unroll
        for (int r = 0; r < 4; r++)
            Zout[(nt * 16 + l15) * 65 + m0 + quad * 4 + r] = Zo[nt][r];
    __syncthreads();
    {
        int pl = t & 63;
        int q = qb + pl;
        if (q < Q) {
            #pragma unroll
            for (int it = 0; it < 32; it++) {
                int n = it * 4 + (t >> 6);
                out[n * Q + q] = Zout[n * 65 + pl];
            }
        }
    }
}

extern "C" void kernel_launch(void* const* d_in, const int* in_sizes, int n_in,
                              void* d_out, int out_size, void* d_ws, size_t ws_size,
                              hipStream_t stream) {
    (void)in_sizes; (void)n_in; (void)out_size;
    const float* q      = (const float*)d_in[0];
    const float* k      = (const float*)d_in[1];
    const float* v      = (const float*)d_in[2];
    const float* Wl     = (const float*)d_in[3];
    const int*   vis    = (const int*)  d_in[4];
    const float* skip   = (const float*)d_in[5];
    const float* qn_w   = (const float*)d_in[6];
    const float* qn_b   = (const float*)d_in[7];
    const float* kn_w   = (const float*)d_in[8];
    const float* kn_b   = (const float*)d_in[9];
    const float* vn_w   = (const float*)d_in[10];
    const float* vn_b   = (const float*)d_in[11];
    const float* pre_w  = (const float*)d_in[12];
    const float* pre_b  = (const float*)d_in[13];
    const float* post_w = (const float*)d_in[14];
    const float* post_b = (const float*)d_in[15];
    const float* wq     = (const float*)d_in[16];
    const float* bq     = (const float*)d_in[17];
    const float* wk     = (const float*)d_in[18];
    const float* bk     = (const float*)d_in[19];
    const float* wv     = (const float*)d_in[20];
    const float* bv     = (const float*)d_in[21];
    const float* wp     = (const float*)d_in[22];
    const float* bp     = (const float*)d_in[23];
    const float* w1     = (const float*)d_in[24];
    const float* b1     = (const float*)d_in[25];
    const float* w2     = (const float*)d_in[26];
    const float* b2     = (const float*)d_in[27];
    float* out = (float*)d_out;

    char* ws = (char*)d_ws;
    unsigned short* xq  = (unsigned short*)(ws + 0);          //  2560*128 bf16 (reused as A1 post-attn)
    unsigned short* xk  = (unsigned short*)(ws + 655360);     // 10112*128 bf16
    unsigned short* xv  = (unsigned short*)(ws + 3244032);
    unsigned short* qh  = (unsigned short*)(ws + 5832704);
    unsigned short* kh  = (unsigned short*)(ws + 6488064);
    unsigned short* vhT = (unsigned short*)(ws + 9076736);    // [128][10112] bf16
    unsigned short* wqT = (unsigned short*)(ws + 11665408);
    unsigned short* wkT = (unsigned short*)(ws + 11698176);
    unsigned short* wvT = (unsigned short*)(ws + 11730944);
    unsigned short* wpT = (unsigned short*)(ws + 11763712);
    unsigned short* w1T = (unsigned short*)(ws + 11796480);
    unsigned short* w2T = (unsigned short*)(ws + 11862016);
    unsigned* OpartU    = (unsigned*)(ws + 11927552);         // 19*OPS u32 (padded stride)
    float* lpart        = (float*)(ws + 34874112);            // 19*LPS f32
    unsigned* vbits     = (unsigned*)(ws + 36316672);         // 2500*320 u32 = 3.2 MB
    // A1 [2560][128] bf16 reuses the xq region (dead after proj) — no ws growth
    unsigned* A1u       = (unsigned*)(ws + 0);
    // high-water: ~39.6 MB (packed path) / ~36.3 MB (fallback)

    const bool usebits = (ws_size == 0) || (ws_size >= 39520000ull);

    prep_kernel<<<dim3(usebits ? 3727 : 1227), dim3(256), 0, stream>>>(
        q, k, v, qn_w, qn_b, kn_w, kn_b, vn_w, vn_b, xq, xk, xv,
        wq, wk, wv, wp, w1, w2, wqT, wkT, wvT, wpT, w1T, w2T, vis, vbits);
    proj_kernel<<<dim3(356), dim3(256), 0, stream>>>(xq, xk, xv, wqT, wkT, wvT, bq, bk, bv,
                                                     qh, kh, vhT);
    if (usebits)
        attn_kernel_t<1><<<dim3(40 * SPLITS), dim3(256), 0, stream>>>(
            qh, kh, vhT, Wl, vis, vbits, OpartU, lpart);
    else
        attn_kernel_t<0><<<dim3(40 * SPLITS), dim3(256), 0, stream>>>(
            qh, kh, vhT, Wl, vis, vbits, OpartU, lpart);
    combine_kernel<<<dim3(320), dim3(128), 0, stream>>>(OpartU, lpart, A1u);
    mlp_kernel<<<dim3(40), dim3(256), 0, stream>>>((const unsigned short*)A1u, wpT, bp, skip,
                                                   pre_w, pre_b, w1T, b1, w2T, b2,
                                                   post_w, post_b, out);
}